// Round 2
// baseline (1262.286 us; speedup 1.0000x reference)
//
#include <hip/hip_runtime.h>

#define NN 50000
#define LL 4
#define DD 128
#define KDIM 16
#define EE 800000
#define MM (NN * LL)
#define DECAYF 0.7f
#define EPSF 1e-5f
#define SCAN_CHUNK 512
#define SCAN_NBLK ((NN + SCAN_CHUNK - 1) / SCAN_CHUNK)   // 98

typedef __attribute__((ext_vector_type(8))) short s16x8;   // 8 bf16 (4 VGPRs) MFMA frag
typedef __attribute__((ext_vector_type(4))) float fx4;     // MFMA accumulator

// ---------- bf16 split helpers (RNE) ----------
__device__ __forceinline__ short f2bf(float x) {
    unsigned u = __float_as_uint(x);
    u += 0x7fffu + ((u >> 16) & 1u);
    return (short)(u >> 16);
}
__device__ __forceinline__ float bf2f(short h) {
    return __uint_as_float(((unsigned)(unsigned short)h) << 16);
}

// ---------- CSR build ----------
__global__ void k_zero(int* p, int n) {
    int i = blockIdx.x * 256 + threadIdx.x;
    if (i < n) p[i] = 0;
}
__global__ void k_hist(const int* __restrict__ rows, int* __restrict__ counts) {
    int e = blockIdx.x * 256 + threadIdx.x;
    if (e < EE) atomicAdd(&counts[rows[e]], 1);
}
__global__ void k_scan1(const int* __restrict__ counts, int* __restrict__ offs, int* __restrict__ csum) {
    __shared__ int s[SCAN_CHUNK];
    int i = blockIdx.x * SCAN_CHUNK + threadIdx.x;
    int v = (i < NN) ? counts[i] : 0;
    s[threadIdx.x] = v;
    __syncthreads();
    for (int off = 1; off < SCAN_CHUNK; off <<= 1) {
        int t = (threadIdx.x >= off) ? s[threadIdx.x - off] : 0;
        __syncthreads();
        s[threadIdx.x] += t;
        __syncthreads();
    }
    if (i < NN) offs[i] = s[threadIdx.x] - v;
    if (threadIdx.x == SCAN_CHUNK - 1) csum[blockIdx.x] = s[SCAN_CHUNK - 1];
}
__global__ void k_scan2(int* __restrict__ csum) {
    __shared__ int s[128];
    int v = (threadIdx.x < SCAN_NBLK) ? csum[threadIdx.x] : 0;
    s[threadIdx.x] = v;
    __syncthreads();
    for (int off = 1; off < 128; off <<= 1) {
        int t = (threadIdx.x >= off) ? s[threadIdx.x - off] : 0;
        __syncthreads();
        s[threadIdx.x] += t;
        __syncthreads();
    }
    if (threadIdx.x < SCAN_NBLK) csum[threadIdx.x] = s[threadIdx.x] - v;
}
__global__ void k_scan3(int* __restrict__ offs, const int* __restrict__ csum, int* __restrict__ cursor) {
    int i = blockIdx.x * SCAN_CHUNK + threadIdx.x;
    if (i < NN) {
        int v = offs[i] + csum[blockIdx.x];
        offs[i] = v;
        cursor[i] = v;
    } else if (i == NN) {
        offs[NN] = EE;
    }
}
__global__ void k_fill(const int* __restrict__ rows, const int* __restrict__ cols,
                       const float* __restrict__ vals,
                       int* __restrict__ cursor, int2* __restrict__ cpack) {
    int e = blockIdx.x * 256 + threadIdx.x;
    if (e < EE) {
        int r = rows[e];
        int pos = atomicAdd(&cursor[r], 1);
        cpack[pos] = make_int2(cols[e], __float_as_int(vals[e]));
    }
}

// ---------- weight prep: transpose + bf16 hi/lo split ----------
// out layout (shorts): sWh[16384] sWl | aWh aWl | vWh vWl | l1h[32768] l1l | l2h l2l | kqh[4096] kql
__global__ void k_wprep(const float* __restrict__ sW, const float* __restrict__ aW,
                        const float* __restrict__ vW, const float* __restrict__ w1,
                        const float* __restrict__ w2,
                        const float* __restrict__ wk, const float* __restrict__ wq,
                        short* __restrict__ out) {
    int b = blockIdx.x;   // 400 blocks x 256 threads
    if (b < 384) {
        const float* src; short* h; short* l; int K; int base;
        if (b < 64)       { src = sW; h = out;          l = out + 16384;  K = 128; base = b; }
        else if (b < 128) { src = aW; h = out + 32768;  l = out + 49152;  K = 128; base = b - 64; }
        else if (b < 192) { src = vW; h = out + 65536;  l = out + 81920;  K = 128; base = b - 128; }
        else if (b < 320) { src = w1; h = out + 98304;  l = out + 131072; K = 256; base = b - 192; }
        else              { src = w2; h = out + 163840; l = out + 180224; K = 128; base = b - 320; }
        int idx = base * 256 + threadIdx.x;   // over K*128, row-major [K][128]
        int k = idx >> 7, n = idx & 127;
        float v = src[idx];
        short hh = f2bf(v);
        h[n * K + k] = hh;                    // transposed: [n][K]
        l[n * K + k] = f2bf(v - bf2f(hh));
    } else {
        // kq: cols 0..15 = Wk^T, 16..31 = Wq^T, layout [32][128]
        int idx = (b - 384) * 256 + threadIdx.x;   // < 4096
        int j = idx >> 7, k = idx & 127;
        float v = (j < 16) ? wk[k * KDIM + j] : wq[k * KDIM + (j - 16)];
        short hh = f2bf(v);
        out[196608 + j * 128 + k] = hh;
        out[200704 + j * 128 + k] = f2bf(v - bf2f(hh));
    }
}

// ---------- stage 64x128 f32 rows -> LDS bf16 hi/lo tiles, row stride 136 ----------
__device__ __forceinline__ void stage64(const float* __restrict__ src, int rowbase,
                                        short* __restrict__ h, short* __restrict__ l, int tid) {
    int row = tid >> 2, ko = (tid & 3) * 32;
    const float* gp = src + (size_t)(rowbase + row) * DD + ko;
    short* dh = h + row * 136 + ko;
    short* dl = l + row * 136 + ko;
    #pragma unroll
    for (int j = 0; j < 4; j++) {
        float4 a = *reinterpret_cast<const float4*>(gp + j * 8);
        float4 b = *reinterpret_cast<const float4*>(gp + j * 8 + 4);
        float v[8] = {a.x, a.y, a.z, a.w, b.x, b.y, b.z, b.w};
        s16x8 hv, lv;
        #pragma unroll
        for (int e = 0; e < 8; e++) {
            short hh = f2bf(v[e]);
            hv[e] = hh;
            lv[e] = f2bf(v[e] - bf2f(hh));
        }
        *(s16x8*)(dh + j * 8) = hv;
        *(s16x8*)(dl + j * 8) = lv;
    }
}

// ---------- one 64x128 (M x N) GEMM pass, K=128, bf16x3 split MFMA ----------
// A (hi/lo) in LDS [64][136]; B = W^T (hi/lo) in global [128][wlen], k-offset koff.
// k bijection (ks*32 + kg*8 + i) identical on A and B frags -> dot order-independent.
// C/D layout [m89]: col = lane&15, row = (lane>>4)*4 + reg.
__device__ __forceinline__ void mfma_pass(const short* __restrict__ a0, const short* __restrict__ a1,
                                          const short* __restrict__ Wh, const short* __restrict__ Wl,
                                          int wlen, int koff, int w, int l16, int kg,
                                          fx4 acc[4][2]) {
    #pragma unroll
    for (int ks = 0; ks < 4; ks++) {
        s16x8 ah[4], al[4];
        #pragma unroll
        for (int mt = 0; mt < 4; mt++) {
            int ao = (mt * 16 + l16) * 136 + ks * 32 + kg * 8;
            ah[mt] = *(const s16x8*)(a0 + ao);
            al[mt] = *(const s16x8*)(a1 + ao);
        }
        #pragma unroll
        for (int nt = 0; nt < 2; nt++) {
            int col = w * 32 + nt * 16 + l16;
            int bo = col * wlen + koff + ks * 32 + kg * 8;
            s16x8 bh = *(const s16x8*)(Wh + bo);
            s16x8 bl = *(const s16x8*)(Wl + bo);
            #pragma unroll
            for (int mt = 0; mt < 4; mt++) {
                acc[mt][nt] = __builtin_amdgcn_mfma_f32_16x16x32_bf16(ah[mt], bh, acc[mt][nt], 0, 0, 0);
                acc[mt][nt] = __builtin_amdgcn_mfma_f32_16x16x32_bf16(ah[mt], bl, acc[mt][nt], 0, 0, 0);
                acc[mt][nt] = __builtin_amdgcn_mfma_f32_16x16x32_bf16(al[mt], bh, acc[mt][nt], 0, 0, 0);
            }
        }
    }
}

// ---------- SAGE megakernel: CSR gather + agg@aggW + x@sageW + bias/silu/LN + kq weights ----------
// out_ rows of this block are written only in the epilogue; agg never hits global.
__global__ __launch_bounds__(256, 4) void k_sage(
    const float* __restrict__ x,
    const int* __restrict__ offs, const int2* __restrict__ cpack,
    const short* __restrict__ aWh, const short* __restrict__ aWl,
    const short* __restrict__ sWh, const short* __restrict__ sWl,
    const short* __restrict__ kqh, const short* __restrict__ kql,
    const float* __restrict__ bias, const float* __restrict__ g, const float* __restrict__ bb,
    float* __restrict__ wt_total, float* __restrict__ iw0,
    float* __restrict__ out_) {
    __shared__ __align__(16) short stg[2][64 * 136];   // 34816 B; f32 LN scratch aliases
    float* fscr = (float*)&stg[0][0];
    short* sh = &stg[0][0];
    short* sl = &stg[1][0];
    const int rowbase = blockIdx.x * 64;
    const int tid = threadIdx.x;
    const int w = tid >> 6, lane = tid & 63;
    const int l16 = lane & 15, kg = lane >> 4;

    fx4 acc[4][2];
    #pragma unroll
    for (int mt = 0; mt < 4; mt++)
        #pragma unroll
        for (int nt = 0; nt < 2; nt++) acc[mt][nt] = (fx4){0.f, 0.f, 0.f, 0.f};

    // ---- Phase A: agg gather (each wave: 16 rows, lanes cover d & d+64) ----
    #pragma unroll 1
    for (int rr = 0; rr < 16; rr++) {
        int row = w * 16 + rr;
        int m = rowbase + row;
        int l = m / NN, n = m - l * NN;
        int s = offs[n], e = offs[n + 1];
        const float* xl = x + (size_t)l * NN * DD + lane;
        float a0 = 0.f, a1 = 0.f;
        for (int p = s; p < e; p++) {
            int2 cw = cpack[p];
            float wv = __int_as_float(cw.y);
            const float* xp = xl + (size_t)cw.x * DD;
            a0 += wv * xp[0];
            a1 += wv * xp[64];
        }
        short h0 = f2bf(a0), h1 = f2bf(a1);
        sh[row * 136 + lane] = h0;       sl[row * 136 + lane] = f2bf(a0 - bf2f(h0));
        sh[row * 136 + 64 + lane] = h1;  sl[row * 136 + 64 + lane] = f2bf(a1 - bf2f(h1));
    }
    __syncthreads();
    mfma_pass(sh, sl, aWh, aWl, 128, 0, w, l16, kg, acc);
    __syncthreads();

    // ---- Phase B: x tile -> sage W + kq ----
    stage64(x, rowbase, sh, sl, tid);
    __syncthreads();
    mfma_pass(sh, sl, sWh, sWl, 128, 0, w, l16, kg, acc);

    // kq: rows of this wave's 16-block only (mt = w), 32 cols (k | q)
    fx4 acck[2];
    acck[0] = (fx4){0.f, 0.f, 0.f, 0.f};
    acck[1] = (fx4){0.f, 0.f, 0.f, 0.f};
    #pragma unroll
    for (int ks = 0; ks < 4; ks++) {
        int ao = (w * 16 + l16) * 136 + ks * 32 + kg * 8;
        s16x8 ah = *(const s16x8*)(sh + ao);
        s16x8 al = *(const s16x8*)(sl + ao);
        #pragma unroll
        for (int nt = 0; nt < 2; nt++) {
            int bo = (nt * 16 + l16) * 128 + ks * 32 + kg * 8;
            s16x8 bh = *(const s16x8*)(kqh + bo);
            s16x8 bl = *(const s16x8*)(kql + bo);
            acck[nt] = __builtin_amdgcn_mfma_f32_16x16x32_bf16(ah, bh, acck[nt], 0, 0, 0);
            acck[nt] = __builtin_amdgcn_mfma_f32_16x16x32_bf16(ah, bl, acck[nt], 0, 0, 0);
            acck[nt] = __builtin_amdgcn_mfma_f32_16x16x32_bf16(al, bh, acck[nt], 0, 0, 0);
        }
    }
    // weights = mean(k*q): k_j in acck[0] (col j=l16), q_j in acck[1] (same lane); sum over 16 lanes
    #pragma unroll
    for (int r = 0; r < 4; r++) {
        float pr = acck[0][r] * acck[1][r];
        pr += __shfl_xor(pr, 1, 64);
        pr += __shfl_xor(pr, 2, 64);
        pr += __shfl_xor(pr, 4, 64);
        pr += __shfl_xor(pr, 8, 64);
        if (l16 == 0) {
            int row = w * 16 + kg * 4 + r;
            int m = rowbase + row;
            int l = m / NN, n = m - l * NN;
            float sv = pr * (1.f / 16.f);
            wt_total[n * LL + l] = sv;
            iw0[n * LL + l] = sv;
        }
    }
    __syncthreads();   // all LDS reads done before fscr overwrite

    // ---- epilogue: +bias, silu -> fscr; LN -> out_ ----
    float bias_r[2];
    #pragma unroll
    for (int nt = 0; nt < 2; nt++) bias_r[nt] = bias[w * 32 + nt * 16 + l16];
    #pragma unroll
    for (int mt = 0; mt < 4; mt++) {
        #pragma unroll
        for (int r = 0; r < 4; r++) {
            int row = mt * 16 + kg * 4 + r;
            #pragma unroll
            for (int nt = 0; nt < 2; nt++) {
                int col = w * 32 + nt * 16 + l16;
                float y = acc[mt][nt][r] + bias_r[nt];
                y = y / (1.f + expf(-y));
                fscr[row * 129 + col] = y;
            }
        }
    }
    __syncthreads();
    {
        float g0 = g[lane], g1 = g[64 + lane];
        float b0 = bb[lane], b1 = bb[64 + lane];
        #pragma unroll 1
        for (int rr = 0; rr < 16; rr++) {
            int row = w * 16 + rr;
            size_t m = (size_t)rowbase + row;
            float y0 = fscr[row * 129 + lane], y1 = fscr[row * 129 + 64 + lane];
            float s = y0 + y1, q = y0 * y0 + y1 * y1;
            #pragma unroll
            for (int off = 32; off; off >>= 1) {
                s += __shfl_xor(s, off, 64);
                q += __shfl_xor(q, off, 64);
            }
            float mean = s * (1.f / 128.f);
            float var = fmaxf(q * (1.f / 128.f) - mean * mean, 0.f);
            float rstd = rsqrtf(var + EPSF);
            out_[m * DD + lane]      = (y0 - mean) * rstd * g0 + b0;
            out_[m * DD + 64 + lane] = (y1 - mean) * rstd * g1 + b1;
        }
    }
}

// ---------- lin1 with inline att branch (MFMA) + T14 reg-prefetch of sage_io ----------
__global__ __launch_bounds__(256, 2) void k_lin1(
    const float* __restrict__ x,
    const short* __restrict__ Wvh, const short* __restrict__ Wvl,
    const float* __restrict__ wtbuf,
    const float* __restrict__ att_g, const float* __restrict__ att_b,
    float* __restrict__ sage_io,
    const short* __restrict__ W1h, const short* __restrict__ W1l,   // [128][256] transposed
    const float* __restrict__ bias,
    const float* __restrict__ g, const float* __restrict__ bb) {
    __shared__ __align__(16) short stg[2][64 * 136];   // staging + f32 LN scratch alias
    __shared__ __align__(16) short atl[2][64 * 136];   // att LN output, persists
    float* fscr = (float*)&stg[0][0];
    const int rowbase = blockIdx.x * 64;
    const int tid = threadIdx.x;
    const int w = tid >> 6, lane = tid & 63;
    const int l16 = lane & 15, kg = lane >> 4;

    // T14: issue sage_io loads now; consumed (convert+LDS write) much later.
    float4 pf[8];
    {
        int row = tid >> 2, ko = (tid & 3) * 32;
        const float* gp = sage_io + (size_t)(rowbase + row) * DD + ko;
        #pragma unroll
        for (int j = 0; j < 8; j++) pf[j] = *reinterpret_cast<const float4*>(gp + j * 4);
    }

    fx4 acc[4][2];
    #pragma unroll
    for (int mt = 0; mt < 4; mt++)
        #pragma unroll
        for (int nt = 0; nt < 2; nt++) acc[mt][nt] = (fx4){0.f, 0.f, 0.f, 0.f};

    // ---- att: x @ Wv ----
    stage64(x, rowbase, &stg[0][0], &stg[1][0], tid);
    __syncthreads();
    mfma_pass(&stg[0][0], &stg[1][0], Wvh, Wvl, 128, 0, w, l16, kg, acc);
    __syncthreads();   // all A-frag reads of stg done before fscr overwrite

    #pragma unroll
    for (int mt = 0; mt < 4; mt++) {
        #pragma unroll
        for (int r = 0; r < 4; r++) {
            int row = mt * 16 + kg * 4 + r;
            int m = rowbase + row;
            int l = m / NN, n = m - l * NN;
            float ws = wtbuf[n * LL + l];
            #pragma unroll
            for (int nt = 0; nt < 2; nt++) {
                int col = w * 32 + nt * 16 + l16;
                fscr[row * 129 + col] = acc[mt][nt][r] * ws;
            }
        }
    }
    __syncthreads();
    {   // att LN -> atl (bf16 hi/lo, stride 136)
        float g0 = att_g[lane], g1 = att_g[64 + lane];
        float b0 = att_b[lane], b1 = att_b[64 + lane];
        #pragma unroll 1
        for (int rr = 0; rr < 16; rr++) {
            int row = w * 16 + rr;
            float y0 = fscr[row * 129 + lane], y1 = fscr[row * 129 + 64 + lane];
            float s = y0 + y1, q = y0 * y0 + y1 * y1;
            #pragma unroll
            for (int off = 32; off; off >>= 1) {
                s += __shfl_xor(s, off, 64);
                q += __shfl_xor(q, off, 64);
            }
            float mean = s * (1.f / 128.f);
            float var = fmaxf(q * (1.f / 128.f) - mean * mean, 0.f);
            float rstd = rsqrtf(var + EPSF);
            float z0 = (y0 - mean) * rstd * g0 + b0;
            float z1 = (y1 - mean) * rstd * g1 + b1;
            short h0 = f2bf(z0), h1 = f2bf(z1);
            atl[0][row * 136 + lane]      = h0;
            atl[1][row * 136 + lane]      = f2bf(z0 - bf2f(h0));
            atl[0][row * 136 + 64 + lane] = h1;
            atl[1][row * 136 + 64 + lane] = f2bf(z1 - bf2f(h1));
        }
    }
    __syncthreads();   // fscr reads done before restage

    // ---- restage sage tile from prefetched regs ----
    {
        int row = tid >> 2, ko = (tid & 3) * 32;
        short* dh = &stg[0][0] + row * 136 + ko;
        short* dl = &stg[1][0] + row * 136 + ko;
        #pragma unroll
        for (int j = 0; j < 4; j++) {
            float v[8] = {pf[2 * j].x, pf[2 * j].y, pf[2 * j].z, pf[2 * j].w,
                          pf[2 * j + 1].x, pf[2 * j + 1].y, pf[2 * j + 1].z, pf[2 * j + 1].w};
            s16x8 hv, lv;
            #pragma unroll
            for (int e = 0; e < 8; e++) {
                short hh = f2bf(v[e]);
                hv[e] = hh;
                lv[e] = f2bf(v[e] - bf2f(hh));
            }
            *(s16x8*)(dh + j * 8) = hv;
            *(s16x8*)(dl + j * 8) = lv;
        }
    }
    #pragma unroll
    for (int mt = 0; mt < 4; mt++)
        #pragma unroll
        for (int nt = 0; nt < 2; nt++) acc[mt][nt] = (fx4){0.f, 0.f, 0.f, 0.f};
    __syncthreads();

    // ---- h1 = sage @ W1[:,0:128] + atile @ W1[:,128:256] ----
    mfma_pass(&stg[0][0], &stg[1][0], W1h, W1l, 256, 0, w, l16, kg, acc);
    mfma_pass(&atl[0][0], &atl[1][0], W1h, W1l, 256, 128, w, l16, kg, acc);
    __syncthreads();

    float bias_r[2];
    #pragma unroll
    for (int nt = 0; nt < 2; nt++) bias_r[nt] = bias[w * 32 + nt * 16 + l16];
    #pragma unroll
    for (int mt = 0; mt < 4; mt++) {
        #pragma unroll
        for (int r = 0; r < 4; r++) {
            int row = mt * 16 + kg * 4 + r;
            #pragma unroll
            for (int nt = 0; nt < 2; nt++) {
                int col = w * 32 + nt * 16 + l16;
                float y = acc[mt][nt][r] + bias_r[nt];
                y = y / (1.f + expf(-y));
                fscr[row * 129 + col] = y;
            }
        }
    }
    __syncthreads();
    {
        float g0 = g[lane], g1 = g[64 + lane];
        float b0 = bb[lane], b1 = bb[64 + lane];
        #pragma unroll 1
        for (int rr = 0; rr < 16; rr++) {
            int row = w * 16 + rr;
            size_t m = (size_t)rowbase + row;
            float y0 = fscr[row * 129 + lane], y1 = fscr[row * 129 + 64 + lane];
            float s = y0 + y1, q = y0 * y0 + y1 * y1;
            #pragma unroll
            for (int off = 32; off; off >>= 1) {
                s += __shfl_xor(s, off, 64);
                q += __shfl_xor(q, off, 64);
            }
            float mean = s * (1.f / 128.f);
            float var = fmaxf(q * (1.f / 128.f) - mean * mean, 0.f);
            float rstd = rsqrtf(var + EPSF);
            sage_io[m * DD + lane]      = (y0 - mean) * rstd * g0 + b0;
            sage_io[m * DD + 64 + lane] = (y1 - mean) * rstd * g1 + b1;
        }
    }
}

// ---------- lin2: out = LN(silu(in@W2 + b + res)) ----------
__global__ __launch_bounds__(256, 4) void k_lin2(
    const float* __restrict__ in_, const short* __restrict__ Wh, const short* __restrict__ Wl,
    const float* __restrict__ res_, const float* __restrict__ bias,
    const float* __restrict__ g, const float* __restrict__ bb,
    float* __restrict__ out_) {
    __shared__ __align__(16) short stg[2][64 * 136];
    float* fscr = (float*)&stg[0][0];
    const int rowbase = blockIdx.x * 64;
    const int tid = threadIdx.x;
    const int w = tid >> 6, lane = tid & 63;
    const int l16 = lane & 15, kg = lane >> 4;

    fx4 acc[4][2];
    #pragma unroll
    for (int mt = 0; mt < 4; mt++)
        #pragma unroll
        for (int nt = 0; nt < 2; nt++) acc[mt][nt] = (fx4){0.f, 0.f, 0.f, 0.f};

    stage64(in_, rowbase, &stg[0][0], &stg[1][0], tid);
    __syncthreads();
    mfma_pass(&stg[0][0], &stg[1][0], Wh, Wl, 128, 0, w, l16, kg, acc);
    __syncthreads();

    float bias_r[2];
    #pragma unroll
    for (int nt = 0; nt < 2; nt++) bias_r[nt] = bias[w * 32 + nt * 16 + l16];
    #pragma unroll
    for (int mt = 0; mt < 4; mt++) {
        #pragma unroll
        for (int r = 0; r < 4; r++) {
            int row = mt * 16 + kg * 4 + r;
            size_t m = (size_t)rowbase + row;
            #pragma unroll
            for (int nt = 0; nt < 2; nt++) {
                int col = w * 32 + nt * 16 + l16;
                float y = acc[mt][nt][r] + bias_r[nt] + res_[m * DD + col];
                y = y / (1.f + expf(-y));
                fscr[row * 129 + col] = y;
            }
        }
    }
    __syncthreads();
    {
        float g0 = g[lane], g1 = g[64 + lane];
        float b0 = bb[lane], b1 = bb[64 + lane];
        #pragma unroll 1
        for (int rr = 0; rr < 16; rr++) {
            int row = w * 16 + rr;
            size_t m = (size_t)rowbase + row;
            float y0 = fscr[row * 129 + lane], y1 = fscr[row * 129 + 64 + lane];
            float s = y0 + y1, q = y0 * y0 + y1 * y1;
            #pragma unroll
            for (int off = 32; off; off >>= 1) {
                s += __shfl_xor(s, off, 64);
                q += __shfl_xor(q, off, 64);
            }
            float mean = s * (1.f / 128.f);
            float var = fmaxf(q * (1.f / 128.f) - mean * mean, 0.f);
            float rstd = rsqrtf(var + EPSF);
            out_[m * DD + lane]      = (y0 - mean) * rstd * g0 + b0;
            out_[m * DD + 64 + lane] = (y1 - mean) * rstd * g1 + b1;
        }
    }
}

// ---------- retentive weight iteration ----------
__global__ __launch_bounds__(256) void k_spmm_w(const int* __restrict__ offs, const int2* __restrict__ cpack,
                                                const float* __restrict__ win, float* __restrict__ wout,
                                                float* __restrict__ wtot) {
    int i = blockIdx.x * 256 + threadIdx.x;
    if (i >= NN * LL) return;
    int n = i >> 2, l = i & 3;
    int s = offs[n], e = offs[n + 1];
    float a = 0.f;
    for (int p = s; p < e; p++) {
        int2 cw = cpack[p];
        a += __int_as_float(cw.y) * win[(cw.x << 2) | l];
    }
    a *= DECAYF;
    wout[i] = a;
    wtot[i] += a;
}

extern "C" void kernel_launch(void* const* d_in, const int* in_sizes, int n_in,
                              void* d_out, int out_size, void* d_ws, size_t ws_size,
                              hipStream_t stream) {
    const float* x        = (const float*)d_in[0];
    const int*   ei       = (const int*)d_in[1];
    const float* evals    = (const float*)d_in[2];
    const float* sage_W   = (const float*)d_in[3];
    const float* sage_b   = (const float*)d_in[4];
    const float* sage_aggW= (const float*)d_in[5];
    const float* sage_ln_g= (const float*)d_in[6];
    const float* sage_ln_b= (const float*)d_in[7];
    const float* att_Wk   = (const float*)d_in[8];
    const float* att_Wq   = (const float*)d_in[9];
    const float* att_Wv   = (const float*)d_in[10];
    const float* att_ln_g = (const float*)d_in[11];
    const float* att_ln_b = (const float*)d_in[12];
    const float* lin1_W   = (const float*)d_in[13];
    const float* lin1_b   = (const float*)d_in[14];
    const float* lin2_W   = (const float*)d_in[15];
    const float* lin2_b   = (const float*)d_in[16];
    const float* ln1_g    = (const float*)d_in[17];
    const float* ln1_b    = (const float*)d_in[18];
    const float* ln2_g    = (const float*)d_in[19];
    const float* ln2_b    = (const float*)d_in[20];

    const int* rows = ei;
    const int* cols = ei + EE;

    // ---- workspace: ~9.8 MB ----
    float* wt_total = (float*)d_ws;                       // [N*L]
    float* iw0      = wt_total + MM;
    float* iw1      = iw0 + MM;
    int*   counts   = (int*)(iw1 + MM);                   // N
    int*   offs     = counts + NN;                        // N+1
    int*   cursor   = offs + NN + 1;                      // N
    int*   csum     = cursor + NN;                        // 128
    uintptr_t pc    = (uintptr_t)(csum + 128);
    pc = (pc + 15) & ~(uintptr_t)15;
    int2*  cpack    = (int2*)pc;                          // E (col, valbits)
    uintptr_t pw    = (uintptr_t)(cpack + EE);
    pw = (pw + 15) & ~(uintptr_t)15;
    short* wbf      = (short*)pw;                         // 204800 shorts (bf16 W^T hi/lo)
    float* io       = (float*)d_out;                      // [M,D] f32: sage -> h1 -> out

    // ---- weight transpose+split (independent of everything else) ----
    k_wprep<<<400, 256, 0, stream>>>(sage_W, sage_aggW, att_Wv, lin1_W, lin2_W,
                                     att_Wk, att_Wq, wbf);

    // ---- CSR build ----
    k_zero<<<(NN + 255) / 256, 256, 0, stream>>>(counts, NN);
    k_hist<<<(EE + 255) / 256, 256, 0, stream>>>(rows, counts);
    k_scan1<<<SCAN_NBLK, SCAN_CHUNK, 0, stream>>>(counts, offs, csum);
    k_scan2<<<1, 128, 0, stream>>>(csum);
    k_scan3<<<SCAN_NBLK, SCAN_CHUNK, 0, stream>>>(offs, csum, cursor);
    k_fill<<<(EE + 255) / 256, 256, 0, stream>>>(rows, cols, evals, cursor, cpack);

    // ---- SAGE megakernel (gather + 2 GEMMs + LN) + kq weights ----
    k_sage<<<MM / 64, 256, 0, stream>>>(
        x, offs, cpack,
        wbf + 32768, wbf + 49152,      // aggW
        wbf, wbf + 16384,              // sageW
        wbf + 196608, wbf + 200704,    // kq
        sage_b, sage_ln_g, sage_ln_b,
        wt_total, iw0, io);

    // ---- retentive weight iterations ----
    k_spmm_w<<<(MM + 255) / 256, 256, 0, stream>>>(offs, cpack, iw0, iw1, wt_total);
    k_spmm_w<<<(MM + 255) / 256, 256, 0, stream>>>(offs, cpack, iw1, iw0, wt_total);

    // ---- h1 = LN(silu(sage@W1a + LN((x@Wv)*w)@W1b + b)) -> io in-place ----
    k_lin1<<<MM / 64, 256, 0, stream>>>(
        x, wbf + 65536, wbf + 81920, wt_total, att_ln_g, att_ln_b, io,
        wbf + 98304, wbf + 131072, lin1_b, ln1_g, ln1_b);

    // ---- out = LN(silu(h1@lin2 + b + x)) -> io (= d_out) in-place ----
    k_lin2<<<MM / 64, 256, 0, stream>>>(
        io, wbf + 163840, wbf + 180224, x, lin2_b, ln2_g, ln2_b, io);

    (void)in_sizes; (void)n_in; (void)out_size; (void)ws_size;
}

// Round 4
// 852.116 us; speedup vs baseline: 1.4814x; 1.4814x over previous
//
#include <hip/hip_runtime.h>
#include <hip/hip_fp16.h>

#define NN 50000
#define LL 4
#define DD 128
#define KDIM 16
#define EE 800000
#define MM (NN * LL)
#define DECAYF 0.7f
#define EPSF 1e-5f
#define SCAN_CHUNK 512
#define SCAN_NBLK ((NN + SCAN_CHUNK - 1) / SCAN_CHUNK)   // 98

typedef __attribute__((ext_vector_type(8))) short s16x8;   // 8 bf16 (4 VGPRs) MFMA frag
typedef __attribute__((ext_vector_type(4))) float fx4;     // MFMA accumulator

// ---------- bf16 split helpers (RNE) ----------
__device__ __forceinline__ short f2bf(float x) {
    unsigned u = __float_as_uint(x);
    u += 0x7fffu + ((u >> 16) & 1u);
    return (short)(u >> 16);
}
__device__ __forceinline__ float bf2f(short h) {
    return __uint_as_float(((unsigned)(unsigned short)h) << 16);
}

// ---------- CSR build ----------
__global__ void k_zero(int* p, int n) {
    int i = blockIdx.x * 256 + threadIdx.x;
    if (i < n) p[i] = 0;
}
__global__ void k_hist(const int* __restrict__ rows, int* __restrict__ counts) {
    int e = blockIdx.x * 256 + threadIdx.x;
    if (e < EE) atomicAdd(&counts[rows[e]], 1);
}
__global__ void k_scan1(const int* __restrict__ counts, int* __restrict__ offs, int* __restrict__ csum) {
    __shared__ int s[SCAN_CHUNK];
    int i = blockIdx.x * SCAN_CHUNK + threadIdx.x;
    int v = (i < NN) ? counts[i] : 0;
    s[threadIdx.x] = v;
    __syncthreads();
    for (int off = 1; off < SCAN_CHUNK; off <<= 1) {
        int t = (threadIdx.x >= off) ? s[threadIdx.x - off] : 0;
        __syncthreads();
        s[threadIdx.x] += t;
        __syncthreads();
    }
    if (i < NN) offs[i] = s[threadIdx.x] - v;
    if (threadIdx.x == SCAN_CHUNK - 1) csum[blockIdx.x] = s[SCAN_CHUNK - 1];
}
__global__ void k_scan2(int* __restrict__ csum) {
    __shared__ int s[128];
    int v = (threadIdx.x < SCAN_NBLK) ? csum[threadIdx.x] : 0;
    s[threadIdx.x] = v;
    __syncthreads();
    for (int off = 1; off < 128; off <<= 1) {
        int t = (threadIdx.x >= off) ? s[threadIdx.x - off] : 0;
        __syncthreads();
        s[threadIdx.x] += t;
        __syncthreads();
    }
    if (threadIdx.x < SCAN_NBLK) csum[threadIdx.x] = s[threadIdx.x] - v;
}
__global__ void k_scan3(int* __restrict__ offs, const int* __restrict__ csum, int* __restrict__ cursor) {
    int i = blockIdx.x * SCAN_CHUNK + threadIdx.x;
    if (i < NN) {
        int v = offs[i] + csum[blockIdx.x];
        offs[i] = v;
        cursor[i] = v;
    } else if (i == NN) {
        offs[NN] = EE;
    }
}
// pack: (col, f32 val) — f32 vals are REQUIRED: the retentive-weight path is
// sign-sensitive (LN cancels |w|), fp16 vals flip signs of near-zero weights.
__global__ void k_fill(const int* __restrict__ rows, const int* __restrict__ cols,
                       const float* __restrict__ vals,
                       int* __restrict__ cursor, int2* __restrict__ cpack) {
    int e = blockIdx.x * 256 + threadIdx.x;
    if (e < EE) {
        int r = rows[e];
        int pos = atomicAdd(&cursor[r], 1);
        cpack[pos] = make_int2(cols[e], __float_as_int(vals[e]));
    }
}

// ---------- x f32 -> fp16 ----------
__global__ __launch_bounds__(256) void k_xhalf(const float* __restrict__ x, __half* __restrict__ xh) {
    size_t i = (size_t)blockIdx.x * 256 + threadIdx.x;   // over M*D/4 = 6.4M
    float4 v = *reinterpret_cast<const float4*>(x + i * 4);
    __half2 h0 = __floats2half2_rn(v.x, v.y);
    __half2 h1 = __floats2half2_rn(v.z, v.w);
    __half2* d = reinterpret_cast<__half2*>(xh + i * 4);
    d[0] = h0;
    d[1] = h1;
}

// ---------- SAGE aggregation (fp16 x gather, f32 vals/accum) -> agg f32 ----------
// 128 thr: hf = tid>>6 picks slice-pair {0,1}/{2,3}; lane covers 2 cols via half2.
__global__ __launch_bounds__(128) void k_agg_h(const int* __restrict__ offs,
                                               const int2* __restrict__ cpack,
                                               const __half* __restrict__ xh,
                                               float* __restrict__ agg) {
    int n = blockIdx.x;
    int hf = threadIdx.x >> 6;
    int lane = threadIdx.x & 63;
    int s = offs[n], e = offs[n + 1];
    const __half* b0 = xh + (size_t)(2 * hf) * NN * DD + lane * 2;
    const __half* b1 = xh + (size_t)(2 * hf + 1) * NN * DD + lane * 2;
    float a00 = 0.f, a01 = 0.f, a10 = 0.f, a11 = 0.f;
    #pragma unroll 2
    for (int p = s; p < e; p++) {
        int2 cw = cpack[p];
        int c = cw.x;
        float wv = __int_as_float(cw.y);
        float2 f0 = __half22float2(*reinterpret_cast<const __half2*>(b0 + (size_t)c * DD));
        float2 f1 = __half22float2(*reinterpret_cast<const __half2*>(b1 + (size_t)c * DD));
        a00 += wv * f0.x; a01 += wv * f0.y;
        a10 += wv * f1.x; a11 += wv * f1.y;
    }
    *reinterpret_cast<float2*>(agg + ((size_t)(2 * hf) * NN + n) * DD + lane * 2)     = make_float2(a00, a01);
    *reinterpret_cast<float2*>(agg + ((size_t)(2 * hf + 1) * NN + n) * DD + lane * 2) = make_float2(a10, a11);
}

// ---------- fallback f32 gather (small workspace) ----------
__global__ __launch_bounds__(128) void k_agg_f(const int* __restrict__ offs,
                                               const int2* __restrict__ cpack,
                                               const float* __restrict__ x,
                                               float* __restrict__ agg) {
    int n = blockIdx.x;
    int tid = threadIdx.x;    // = d
    int s = offs[n], e = offs[n + 1];
    float a0 = 0.f, a1 = 0.f, a2 = 0.f, a3 = 0.f;
    for (int p = s; p < e; p++) {
        int2 cw = cpack[p];
        int c = cw.x;
        float w = __int_as_float(cw.y);
        a0 += w * x[((size_t)(0 * NN + c)) * DD + tid];
        a1 += w * x[((size_t)(1 * NN + c)) * DD + tid];
        a2 += w * x[((size_t)(2 * NN + c)) * DD + tid];
        a3 += w * x[((size_t)(3 * NN + c)) * DD + tid];
    }
    agg[((size_t)(0 * NN + n)) * DD + tid] = a0;
    agg[((size_t)(1 * NN + n)) * DD + tid] = a1;
    agg[((size_t)(2 * NN + n)) * DD + tid] = a2;
    agg[((size_t)(3 * NN + n)) * DD + tid] = a3;
}

// ---------- weight prep: transpose + bf16 hi/lo split ----------
// out layout (shorts): sWh[16384] sWl | aWh aWl | vWh vWl | l1h[32768] l1l | l2h l2l | kqh[4096] kql
__global__ void k_wprep(const float* __restrict__ sW, const float* __restrict__ aW,
                        const float* __restrict__ vW, const float* __restrict__ w1,
                        const float* __restrict__ w2,
                        const float* __restrict__ wk, const float* __restrict__ wq,
                        short* __restrict__ out) {
    int b = blockIdx.x;   // 400 blocks x 256 threads
    if (b < 384) {
        const float* src; short* h; short* l; int K; int base;
        if (b < 64)       { src = sW; h = out;          l = out + 16384;  K = 128; base = b; }
        else if (b < 128) { src = aW; h = out + 32768;  l = out + 49152;  K = 128; base = b - 64; }
        else if (b < 192) { src = vW; h = out + 65536;  l = out + 81920;  K = 128; base = b - 128; }
        else if (b < 320) { src = w1; h = out + 98304;  l = out + 131072; K = 256; base = b - 192; }
        else              { src = w2; h = out + 163840; l = out + 180224; K = 128; base = b - 320; }
        int idx = base * 256 + threadIdx.x;   // over K*128, row-major [K][128]
        int k = idx >> 7, n = idx & 127;
        float v = src[idx];
        short hh = f2bf(v);
        h[n * K + k] = hh;                    // transposed: [n][K]
        l[n * K + k] = f2bf(v - bf2f(hh));
    } else {
        // kq: cols 0..15 = Wk^T, 16..31 = Wq^T, layout [32][128]
        int idx = (b - 384) * 256 + threadIdx.x;   // < 4096
        int j = idx >> 7, k = idx & 127;
        float v = (j < 16) ? wk[k * KDIM + j] : wq[k * KDIM + (j - 16)];
        short hh = f2bf(v);
        out[196608 + j * 128 + k] = hh;
        out[200704 + j * 128 + k] = f2bf(v - bf2f(hh));
    }
}

// ---------- stage 64x128 f32 rows -> LDS bf16 hi/lo tiles, row stride 136 ----------
__device__ __forceinline__ void stage64(const float* __restrict__ src, int rowbase,
                                        short* __restrict__ h, short* __restrict__ l, int tid) {
    int row = tid >> 2, ko = (tid & 3) * 32;
    const float* gp = src + (size_t)(rowbase + row) * DD + ko;
    short* dh = h + row * 136 + ko;
    short* dl = l + row * 136 + ko;
    #pragma unroll
    for (int j = 0; j < 4; j++) {
        float4 a = *reinterpret_cast<const float4*>(gp + j * 8);
        float4 b = *reinterpret_cast<const float4*>(gp + j * 8 + 4);
        float v[8] = {a.x, a.y, a.z, a.w, b.x, b.y, b.z, b.w};
        s16x8 hv, lv;
        #pragma unroll
        for (int e = 0; e < 8; e++) {
            short hh = f2bf(v[e]);
            hv[e] = hh;
            lv[e] = f2bf(v[e] - bf2f(hh));
        }
        *(s16x8*)(dh + j * 8) = hv;
        *(s16x8*)(dl + j * 8) = lv;
    }
}

// ---------- one 64x128 (M x N) GEMM pass, K=128, bf16x3 split MFMA ----------
// A (hi/lo) in LDS [64][136]; B = W^T (hi/lo) in global [128][wlen], k-offset koff.
// k bijection (ks*32 + kg*8 + i) identical on A and B frags -> dot order-independent.
// C/D layout [m89]: col = lane&15, row = (lane>>4)*4 + reg.
__device__ __forceinline__ void mfma_pass(const short* __restrict__ a0, const short* __restrict__ a1,
                                          const short* __restrict__ Wh, const short* __restrict__ Wl,
                                          int wlen, int koff, int w, int l16, int kg,
                                          fx4 acc[4][2]) {
    #pragma unroll
    for (int ks = 0; ks < 4; ks++) {
        s16x8 ah[4], al[4];
        #pragma unroll
        for (int mt = 0; mt < 4; mt++) {
            int ao = (mt * 16 + l16) * 136 + ks * 32 + kg * 8;
            ah[mt] = *(const s16x8*)(a0 + ao);
            al[mt] = *(const s16x8*)(a1 + ao);
        }
        #pragma unroll
        for (int nt = 0; nt < 2; nt++) {
            int col = w * 32 + nt * 16 + l16;
            int bo = col * wlen + koff + ks * 32 + kg * 8;
            s16x8 bh = *(const s16x8*)(Wh + bo);
            s16x8 bl = *(const s16x8*)(Wl + bo);
            #pragma unroll
            for (int mt = 0; mt < 4; mt++) {
                acc[mt][nt] = __builtin_amdgcn_mfma_f32_16x16x32_bf16(ah[mt], bh, acc[mt][nt], 0, 0, 0);
                acc[mt][nt] = __builtin_amdgcn_mfma_f32_16x16x32_bf16(ah[mt], bl, acc[mt][nt], 0, 0, 0);
                acc[mt][nt] = __builtin_amdgcn_mfma_f32_16x16x32_bf16(al[mt], bh, acc[mt][nt], 0, 0, 0);
            }
        }
    }
}

// ---------- sage GEMMs + kq piggyback: io = LN(silu(agg@aggW + x@sageW + b)), wt = mean(k*q) ----------
// io holds agg on entry; in-place safe (row-local).
__global__ __launch_bounds__(256, 4) void k_sage2(
    const float* __restrict__ x,
    const short* __restrict__ aWh, const short* __restrict__ aWl,
    const short* __restrict__ sWh, const short* __restrict__ sWl,
    const short* __restrict__ kqh, const short* __restrict__ kql,
    const float* __restrict__ bias, const float* __restrict__ g, const float* __restrict__ bb,
    float* __restrict__ wt_total, float* __restrict__ iw0,
    float* __restrict__ io) {
    __shared__ __align__(16) short stg[2][64 * 136];   // 34816 B; f32 LN scratch aliases
    float* fscr = (float*)&stg[0][0];
    short* sh = &stg[0][0];
    short* sl = &stg[1][0];
    const int rowbase = blockIdx.x * 64;
    const int tid = threadIdx.x;
    const int w = tid >> 6, lane = tid & 63;
    const int l16 = lane & 15, kg = lane >> 4;

    fx4 acc[4][2];
    #pragma unroll
    for (int mt = 0; mt < 4; mt++)
        #pragma unroll
        for (int nt = 0; nt < 2; nt++) acc[mt][nt] = (fx4){0.f, 0.f, 0.f, 0.f};

    // ---- agg tile (from io) @ aggW ----
    stage64(io, rowbase, sh, sl, tid);
    __syncthreads();
    mfma_pass(sh, sl, aWh, aWl, 128, 0, w, l16, kg, acc);
    __syncthreads();

    // ---- x tile @ sageW + kq piggyback ----
    stage64(x, rowbase, sh, sl, tid);
    __syncthreads();
    mfma_pass(sh, sl, sWh, sWl, 128, 0, w, l16, kg, acc);

    fx4 acck[2];
    acck[0] = (fx4){0.f, 0.f, 0.f, 0.f};
    acck[1] = (fx4){0.f, 0.f, 0.f, 0.f};
    #pragma unroll
    for (int ks = 0; ks < 4; ks++) {
        int ao = (w * 16 + l16) * 136 + ks * 32 + kg * 8;
        s16x8 ah = *(const s16x8*)(sh + ao);
        s16x8 al = *(const s16x8*)(sl + ao);
        #pragma unroll
        for (int nt = 0; nt < 2; nt++) {
            int bo = (nt * 16 + l16) * 128 + ks * 32 + kg * 8;
            s16x8 bh = *(const s16x8*)(kqh + bo);
            s16x8 bl = *(const s16x8*)(kql + bo);
            acck[nt] = __builtin_amdgcn_mfma_f32_16x16x32_bf16(ah, bh, acck[nt], 0, 0, 0);
            acck[nt] = __builtin_amdgcn_mfma_f32_16x16x32_bf16(ah, bl, acck[nt], 0, 0, 0);
            acck[nt] = __builtin_amdgcn_mfma_f32_16x16x32_bf16(al, bh, acck[nt], 0, 0, 0);
        }
    }
    // weights = mean(k*q): k in acck[0], q in acck[1] (same lane/col); sum over 16 cols
    #pragma unroll
    for (int r = 0; r < 4; r++) {
        float pr = acck[0][r] * acck[1][r];
        pr += __shfl_xor(pr, 1, 64);
        pr += __shfl_xor(pr, 2, 64);
        pr += __shfl_xor(pr, 4, 64);
        pr += __shfl_xor(pr, 8, 64);
        if (l16 == 0) {
            int row = w * 16 + kg * 4 + r;
            int m = rowbase + row;
            int l = m / NN, n = m - l * NN;
            float sv = pr * (1.f / 16.f);
            wt_total[n * LL + l] = sv;
            iw0[n * LL + l] = sv;
        }
    }
    __syncthreads();   // all LDS reads done before fscr overwrite

    // ---- epilogue: +bias, silu -> fscr; LN -> io ----
    float bias_r[2];
    #pragma unroll
    for (int nt = 0; nt < 2; nt++) bias_r[nt] = bias[w * 32 + nt * 16 + l16];
    #pragma unroll
    for (int mt = 0; mt < 4; mt++) {
        #pragma unroll
        for (int r = 0; r < 4; r++) {
            int row = mt * 16 + kg * 4 + r;
            #pragma unroll
            for (int nt = 0; nt < 2; nt++) {
                int col = w * 32 + nt * 16 + l16;
                float y = acc[mt][nt][r] + bias_r[nt];
                y = y / (1.f + expf(-y));
                fscr[row * 129 + col] = y;
            }
        }
    }
    __syncthreads();
    {
        float g0 = g[lane], g1 = g[64 + lane];
        float b0 = bb[lane], b1 = bb[64 + lane];
        #pragma unroll 1
        for (int rr = 0; rr < 16; rr++) {
            int row = w * 16 + rr;
            size_t m = (size_t)rowbase + row;
            float y0 = fscr[row * 129 + lane], y1 = fscr[row * 129 + 64 + lane];
            float s = y0 + y1, q = y0 * y0 + y1 * y1;
            #pragma unroll
            for (int off = 32; off; off >>= 1) {
                s += __shfl_xor(s, off, 64);
                q += __shfl_xor(q, off, 64);
            }
            float mean = s * (1.f / 128.f);
            float var = fmaxf(q * (1.f / 128.f) - mean * mean, 0.f);
            float rstd = rsqrtf(var + EPSF);
            io[m * DD + lane]      = (y0 - mean) * rstd * g0 + b0;
            io[m * DD + 64 + lane] = (y1 - mean) * rstd * g1 + b1;
        }
    }
}

// ---------- fused lin1 + lin2: att branch, h1 (LDS only), out = LN2(silu(h1@W2 + b2 + x)) ----------
__global__ __launch_bounds__(256, 2) void k_lin12(
    const float* __restrict__ x,
    const short* __restrict__ Wvh, const short* __restrict__ Wvl,
    const float* __restrict__ wtbuf,
    const float* __restrict__ att_g, const float* __restrict__ att_b,
    const short* __restrict__ W1h, const short* __restrict__ W1l,   // [128][256] transposed
    const float* __restrict__ b1v,
    const float* __restrict__ ln1g, const float* __restrict__ ln1b,
    const short* __restrict__ W2h, const short* __restrict__ W2l,   // [128][128] transposed
    const float* __restrict__ b2v,
    const float* __restrict__ ln2g, const float* __restrict__ ln2b,
    float* __restrict__ io) {                                        // sage in, out in-place
    __shared__ __align__(16) short stg[2][64 * 136];   // staging + f32 LN scratch alias
    __shared__ __align__(16) short atl[2][64 * 136];   // att-LN / h1-LN bf16 tiles
    float* fscr = (float*)&stg[0][0];
    const int rowbase = blockIdx.x * 64;
    const int tid = threadIdx.x;
    const int w = tid >> 6, lane = tid & 63;
    const int l16 = lane & 15, kg = lane >> 4;

    // T14: issue sage loads now; consumed at restage much later.
    float4 pf[8];
    {
        int row = tid >> 2, ko = (tid & 3) * 32;
        const float* gp = io + (size_t)(rowbase + row) * DD + ko;
        #pragma unroll
        for (int j = 0; j < 8; j++) pf[j] = *reinterpret_cast<const float4*>(gp + j * 4);
    }

    fx4 acc[4][2];
    #pragma unroll
    for (int mt = 0; mt < 4; mt++)
        #pragma unroll
        for (int nt = 0; nt < 2; nt++) acc[mt][nt] = (fx4){0.f, 0.f, 0.f, 0.f};

    // ---- att: x @ Wv ----
    stage64(x, rowbase, &stg[0][0], &stg[1][0], tid);
    __syncthreads();
    mfma_pass(&stg[0][0], &stg[1][0], Wvh, Wvl, 128, 0, w, l16, kg, acc);
    __syncthreads();

    #pragma unroll
    for (int mt = 0; mt < 4; mt++) {
        #pragma unroll
        for (int r = 0; r < 4; r++) {
            int row = mt * 16 + kg * 4 + r;
            int m = rowbase + row;
            int l = m / NN, n = m - l * NN;
            float ws = wtbuf[n * LL + l];
            #pragma unroll
            for (int nt = 0; nt < 2; nt++) {
                int col = w * 32 + nt * 16 + l16;
                fscr[row * 129 + col] = acc[mt][nt][r] * ws;
            }
        }
    }
    __syncthreads();
    {   // att LN -> atl (bf16 hi/lo)
        float g0 = att_g[lane], g1 = att_g[64 + lane];
        float b0 = att_b[lane], b1 = att_b[64 + lane];
        #pragma unroll 1
        for (int rr = 0; rr < 16; rr++) {
            int row = w * 16 + rr;
            float y0 = fscr[row * 129 + lane], y1 = fscr[row * 129 + 64 + lane];
            float s = y0 + y1, q = y0 * y0 + y1 * y1;
            #pragma unroll
            for (int off = 32; off; off >>= 1) {
                s += __shfl_xor(s, off, 64);
                q += __shfl_xor(q, off, 64);
            }
            float mean = s * (1.f / 128.f);
            float var = fmaxf(q * (1.f / 128.f) - mean * mean, 0.f);
            float rstd = rsqrtf(var + EPSF);
            float z0 = (y0 - mean) * rstd * g0 + b0;
            float z1 = (y1 - mean) * rstd * g1 + b1;
            short h0 = f2bf(z0), h1 = f2bf(z1);
            atl[0][row * 136 + lane]      = h0;
            atl[1][row * 136 + lane]      = f2bf(z0 - bf2f(h0));
            atl[0][row * 136 + 64 + lane] = h1;
            atl[1][row * 136 + 64 + lane] = f2bf(z1 - bf2f(h1));
        }
    }
    __syncthreads();

    // ---- restage sage tile from prefetched regs ----
    {
        int row = tid >> 2, ko = (tid & 3) * 32;
        short* dh = &stg[0][0] + row * 136 + ko;
        short* dl = &stg[1][0] + row * 136 + ko;
        #pragma unroll
        for (int j = 0; j < 4; j++) {
            float v[8] = {pf[2 * j].x, pf[2 * j].y, pf[2 * j].z, pf[2 * j].w,
                          pf[2 * j + 1].x, pf[2 * j + 1].y, pf[2 * j + 1].z, pf[2 * j + 1].w};
            s16x8 hv, lv;
            #pragma unroll
            for (int e = 0; e < 8; e++) {
                short hh = f2bf(v[e]);
                hv[e] = hh;
                lv[e] = f2bf(v[e] - bf2f(hh));
            }
            *(s16x8*)(dh + j * 8) = hv;
            *(s16x8*)(dl + j * 8) = lv;
        }
    }
    #pragma unroll
    for (int mt = 0; mt < 4; mt++)
        #pragma unroll
        for (int nt = 0; nt < 2; nt++) acc[mt][nt] = (fx4){0.f, 0.f, 0.f, 0.f};
    __syncthreads();

    // ---- h1 = sage @ W1[:,0:128] + atile @ W1[:,128:256] ----
    mfma_pass(&stg[0][0], &stg[1][0], W1h, W1l, 256, 0, w, l16, kg, acc);
    mfma_pass(&atl[0][0], &atl[1][0], W1h, W1l, 256, 128, w, l16, kg, acc);
    __syncthreads();

    {   // bias + silu -> fscr
        float bias_r[2];
        #pragma unroll
        for (int nt = 0; nt < 2; nt++) bias_r[nt] = b1v[w * 32 + nt * 16 + l16];
        #pragma unroll
        for (int mt = 0; mt < 4; mt++) {
            #pragma unroll
            for (int r = 0; r < 4; r++) {
                int row = mt * 16 + kg * 4 + r;
                #pragma unroll
                for (int nt = 0; nt < 2; nt++) {
                    int col = w * 32 + nt * 16 + l16;
                    float y = acc[mt][nt][r] + bias_r[nt];
                    y = y / (1.f + expf(-y));
                    fscr[row * 129 + col] = y;
                }
            }
        }
    }
    __syncthreads();
    {   // LN1 -> atl (bf16 hi/lo), h1 stays on-chip
        float g0 = ln1g[lane], g1 = ln1g[64 + lane];
        float b0 = ln1b[lane], b1 = ln1b[64 + lane];
        #pragma unroll 1
        for (int rr = 0; rr < 16; rr++) {
            int row = w * 16 + rr;
            float y0 = fscr[row * 129 + lane], y1 = fscr[row * 129 + 64 + lane];
            float s = y0 + y1, q = y0 * y0 + y1 * y1;
            #pragma unroll
            for (int off = 32; off; off >>= 1) {
                s += __shfl_xor(s, off, 64);
                q += __shfl_xor(q, off, 64);
            }
            float mean = s * (1.f / 128.f);
            float var = fmaxf(q * (1.f / 128.f) - mean * mean, 0.f);
            float rstd = rsqrtf(var + EPSF);
            float z0 = (y0 - mean) * rstd * g0 + b0;
            float z1 = (y1 - mean) * rstd * g1 + b1;
            short h0 = f2bf(z0), h1 = f2bf(z1);
            atl[0][row * 136 + lane]      = h0;
            atl[1][row * 136 + lane]      = f2bf(z0 - bf2f(h0));
            atl[0][row * 136 + 64 + lane] = h1;
            atl[1][row * 136 + 64 + lane] = f2bf(z1 - bf2f(h1));
        }
    }
    __syncthreads();

    // ---- out = LN2(silu(h1 @ W2 + b2 + x)) ----
    #pragma unroll
    for (int mt = 0; mt < 4; mt++)
        #pragma unroll
        for (int nt = 0; nt < 2; nt++) acc[mt][nt] = (fx4){0.f, 0.f, 0.f, 0.f};
    mfma_pass(&atl[0][0], &atl[1][0], W2h, W2l, 128, 0, w, l16, kg, acc);
    // (mfma reads atl; fscr writes below touch stg only — no extra barrier needed)
    {
        float bias_r[2];
        #pragma unroll
        for (int nt = 0; nt < 2; nt++) bias_r[nt] = b2v[w * 32 + nt * 16 + l16];
        #pragma unroll
        for (int mt = 0; mt < 4; mt++) {
            #pragma unroll
            for (int r = 0; r < 4; r++) {
                int row = mt * 16 + kg * 4 + r;
                size_t m = (size_t)rowbase + row;
                #pragma unroll
                for (int nt = 0; nt < 2; nt++) {
                    int col = w * 32 + nt * 16 + l16;
                    float y = acc[mt][nt][r] + bias_r[nt] + x[m * DD + col];   // L2-hot residual
                    y = y / (1.f + expf(-y));
                    fscr[row * 129 + col] = y;
                }
            }
        }
    }
    __syncthreads();
    {
        float g0 = ln2g[lane], g1 = ln2g[64 + lane];
        float b0 = ln2b[lane], b1 = ln2b[64 + lane];
        #pragma unroll 1
        for (int rr = 0; rr < 16; rr++) {
            int row = w * 16 + rr;
            size_t m = (size_t)rowbase + row;
            float y0 = fscr[row * 129 + lane], y1 = fscr[row * 129 + 64 + lane];
            float s = y0 + y1, q = y0 * y0 + y1 * y1;
            #pragma unroll
            for (int off = 32; off; off >>= 1) {
                s += __shfl_xor(s, off, 64);
                q += __shfl_xor(q, off, 64);
            }
            float mean = s * (1.f / 128.f);
            float var = fmaxf(q * (1.f / 128.f) - mean * mean, 0.f);
            float rstd = rsqrtf(var + EPSF);
            io[m * DD + lane]      = (y0 - mean) * rstd * g0 + b0;
            io[m * DD + 64 + lane] = (y1 - mean) * rstd * g1 + b1;
        }
    }
}

// ---------- retentive weight iteration (f32 vals — sign-critical) ----------
__global__ __launch_bounds__(256) void k_spmm_w(const int* __restrict__ offs,
                                                const int2* __restrict__ cpack,
                                                const float* __restrict__ win, float* __restrict__ wout,
                                                float* __restrict__ wtot) {
    int i = blockIdx.x * 256 + threadIdx.x;
    if (i >= NN * LL) return;
    int n = i >> 2, l = i & 3;
    int s = offs[n], e = offs[n + 1];
    float a = 0.f;
    for (int p = s; p < e; p++) {
        int2 cw = cpack[p];
        a += __int_as_float(cw.y) * win[(cw.x << 2) | l];
    }
    a *= DECAYF;
    wout[i] = a;
    wtot[i] += a;
}

extern "C" void kernel_launch(void* const* d_in, const int* in_sizes, int n_in,
                              void* d_out, int out_size, void* d_ws, size_t ws_size,
                              hipStream_t stream) {
    const float* x        = (const float*)d_in[0];
    const int*   ei       = (const int*)d_in[1];
    const float* evals    = (const float*)d_in[2];
    const float* sage_W   = (const float*)d_in[3];
    const float* sage_b   = (const float*)d_in[4];
    const float* sage_aggW= (const float*)d_in[5];
    const float* sage_ln_g= (const float*)d_in[6];
    const float* sage_ln_b= (const float*)d_in[7];
    const float* att_Wk   = (const float*)d_in[8];
    const float* att_Wq   = (const float*)d_in[9];
    const float* att_Wv   = (const float*)d_in[10];
    const float* att_ln_g = (const float*)d_in[11];
    const float* att_ln_b = (const float*)d_in[12];
    const float* lin1_W   = (const float*)d_in[13];
    const float* lin1_b   = (const float*)d_in[14];
    const float* lin2_W   = (const float*)d_in[15];
    const float* lin2_b   = (const float*)d_in[16];
    const float* ln1_g    = (const float*)d_in[17];
    const float* ln1_b    = (const float*)d_in[18];
    const float* ln2_g    = (const float*)d_in[19];
    const float* ln2_b    = (const float*)d_in[20];

    const int* rows = ei;
    const int* cols = ei + EE;

    // ---- workspace layout ----
    float* wt_total = (float*)d_ws;                       // [M]
    float* iw0      = wt_total + MM;
    float* iw1      = iw0 + MM;
    int*   counts   = (int*)(iw1 + MM);                   // N
    int*   offs     = counts + NN;                        // N+1
    int*   cursor   = offs + NN + 1;                      // N
    int*   csum     = cursor + NN;                        // 128
    uintptr_t pc    = (uintptr_t)(csum + 128);
    pc = (pc + 15) & ~(uintptr_t)15;
    int2*  cpack    = (int2*)pc;                          // E (col, f32 valbits)
    uintptr_t pw    = (uintptr_t)(cpack + EE);
    pw = (pw + 15) & ~(uintptr_t)15;
    short* wbf      = (short*)pw;                         // 204800 shorts
    uintptr_t ph    = (uintptr_t)(wbf + 204800);
    ph = (ph + 255) & ~(uintptr_t)255;
    __half* xh      = (__half*)ph;                        // M*D fp16 = 51.2 MB (optional)
    size_t need_h   = (ph - (uintptr_t)d_ws) + (size_t)MM * DD * sizeof(__half);
    bool use_half   = ws_size >= need_h;
    float* io       = (float*)d_out;                      // [M,D] f32: agg -> sage -> out

    // ---- weight transpose+split ----
    k_wprep<<<400, 256, 0, stream>>>(sage_W, sage_aggW, att_Wv, lin1_W, lin2_W,
                                     att_Wk, att_Wq, wbf);

    // ---- CSR build ----
    k_zero<<<(NN + 255) / 256, 256, 0, stream>>>(counts, NN);
    k_hist<<<(EE + 255) / 256, 256, 0, stream>>>(rows, counts);
    k_scan1<<<SCAN_NBLK, SCAN_CHUNK, 0, stream>>>(counts, offs, csum);
    k_scan2<<<1, 128, 0, stream>>>(csum);
    k_scan3<<<SCAN_NBLK, SCAN_CHUNK, 0, stream>>>(offs, csum, cursor);
    k_fill<<<(EE + 255) / 256, 256, 0, stream>>>(rows, cols, evals, cursor, cpack);

    // ---- SAGE aggregation -> io ----
    if (use_half) {
        k_xhalf<<<(MM * DD / 4 + 255) / 256, 256, 0, stream>>>(x, xh);
        k_agg_h<<<NN, 128, 0, stream>>>(offs, cpack, xh, io);
    } else {
        k_agg_f<<<NN, 128, 0, stream>>>(offs, cpack, x, io);
    }

    // ---- sage GEMMs + kq -> io in-place, wt_total/iw0 ----
    k_sage2<<<MM / 64, 256, 0, stream>>>(
        x,
        wbf + 32768, wbf + 49152,      // aggW
        wbf, wbf + 16384,              // sageW
        wbf + 196608, wbf + 200704,    // kq
        sage_b, sage_ln_g, sage_ln_b,
        wt_total, iw0, io);

    // ---- retentive weight iterations ----
    k_spmm_w<<<(MM + 255) / 256, 256, 0, stream>>>(offs, cpack, iw0, iw1, wt_total);
    k_spmm_w<<<(MM + 255) / 256, 256, 0, stream>>>(offs, cpack, iw1, iw0, wt_total);

    // ---- fused lin1+lin2 -> io (= d_out) in-place ----
    k_lin12<<<MM / 64, 256, 0, stream>>>(
        x, wbf + 65536, wbf + 81920, wt_total, att_ln_g, att_ln_b,
        wbf + 98304, wbf + 131072, lin1_b, ln1_g, ln1_b,
        wbf + 163840, wbf + 180224, lin2_b, ln2_g, ln2_b,
        io);

    (void)in_sizes; (void)n_in; (void)out_size;
}

// Round 5
// 771.076 us; speedup vs baseline: 1.6370x; 1.1051x over previous
//
#include <hip/hip_runtime.h>
#include <hip/hip_fp16.h>

#define NN 50000
#define LL 4
#define DD 128
#define KDIM 16
#define EE 800000
#define MM (NN * LL)
#define DECAYF 0.7f
#define EPSF 1e-5f
#define SCAN_CHUNK 512
#define SCAN_NBLK ((NN + SCAN_CHUNK - 1) / SCAN_CHUNK)   // 98

typedef __attribute__((ext_vector_type(8))) short s16x8;   // 8 bf16 (4 VGPRs) MFMA frag
typedef __attribute__((ext_vector_type(4))) float fx4;     // MFMA accumulator

// ---------- bf16 split helpers (RNE) ----------
__device__ __forceinline__ short f2bf(float x) {
    unsigned u = __float_as_uint(x);
    u += 0x7fffu + ((u >> 16) & 1u);
    return (short)(u >> 16);
}
__device__ __forceinline__ float bf2f(short h) {
    return __uint_as_float(((unsigned)(unsigned short)h) << 16);
}
// fast silu: y * rcp(1+exp(-y)); v_rcp_f32 rel err ~2^-22, __expf native — error ~1e-7
__device__ __forceinline__ float silu(float y) {
    return y * __builtin_amdgcn_rcpf(1.f + __expf(-y));
}

// ---------- CSR build ----------
__global__ void k_zero(int* p, int n) {
    int i = blockIdx.x * 256 + threadIdx.x;
    if (i < n) p[i] = 0;
}
__global__ void k_hist(const int* __restrict__ rows, int* __restrict__ counts) {
    int e = blockIdx.x * 256 + threadIdx.x;
    if (e < EE) atomicAdd(&counts[rows[e]], 1);
}
__global__ void k_scan1(const int* __restrict__ counts, int* __restrict__ offs, int* __restrict__ csum) {
    __shared__ int s[SCAN_CHUNK];
    int i = blockIdx.x * SCAN_CHUNK + threadIdx.x;
    int v = (i < NN) ? counts[i] : 0;
    s[threadIdx.x] = v;
    __syncthreads();
    for (int off = 1; off < SCAN_CHUNK; off <<= 1) {
        int t = (threadIdx.x >= off) ? s[threadIdx.x - off] : 0;
        __syncthreads();
        s[threadIdx.x] += t;
        __syncthreads();
    }
    if (i < NN) offs[i] = s[threadIdx.x] - v;
    if (threadIdx.x == SCAN_CHUNK - 1) csum[blockIdx.x] = s[SCAN_CHUNK - 1];
}
__global__ void k_scan2(int* __restrict__ csum) {
    __shared__ int s[128];
    int v = (threadIdx.x < SCAN_NBLK) ? csum[threadIdx.x] : 0;
    s[threadIdx.x] = v;
    __syncthreads();
    for (int off = 1; off < 128; off <<= 1) {
        int t = (threadIdx.x >= off) ? s[threadIdx.x - off] : 0;
        __syncthreads();
        s[threadIdx.x] += t;
        __syncthreads();
    }
    if (threadIdx.x < SCAN_NBLK) csum[threadIdx.x] = s[threadIdx.x] - v;
}
__global__ void k_scan3(int* __restrict__ offs, const int* __restrict__ csum, int* __restrict__ cursor) {
    int i = blockIdx.x * SCAN_CHUNK + threadIdx.x;
    if (i < NN) {
        int v = offs[i] + csum[blockIdx.x];
        offs[i] = v;
        cursor[i] = v;
    } else if (i == NN) {
        offs[NN] = EE;
    }
}
// pack: (col, f32 val) — f32 vals REQUIRED: retentive-weight path is sign-sensitive
// (LN cancels |w|); fp16 vals flip signs of near-zero weights (round-3 failure).
__global__ void k_fill(const int* __restrict__ rows, const int* __restrict__ cols,
                       const float* __restrict__ vals,
                       int* __restrict__ cursor, int2* __restrict__ cpack) {
    int e = blockIdx.x * 256 + threadIdx.x;
    if (e < EE) {
        int r = rows[e];
        int pos = atomicAdd(&cursor[r], 1);
        cpack[pos] = make_int2(cols[e], __float_as_int(vals[e]));
    }
}

// ---------- x f32 -> fp16 ----------
__global__ __launch_bounds__(256) void k_xhalf(const float* __restrict__ x, __half* __restrict__ xh) {
    size_t i = (size_t)blockIdx.x * 256 + threadIdx.x;   // over M*D/4 = 6.4M
    float4 v = *reinterpret_cast<const float4*>(x + i * 4);
    __half2 h0 = __floats2half2_rn(v.x, v.y);
    __half2 h1 = __floats2half2_rn(v.z, v.w);
    __half2* d = reinterpret_cast<__half2*>(xh + i * 4);
    d[0] = h0;
    d[1] = h1;
}

// ---------- SAGE aggregation (fp16 x gather, f32 vals/accum) -> agg f32 ----------
__global__ __launch_bounds__(128) void k_agg_h(const int* __restrict__ offs,
                                               const int2* __restrict__ cpack,
                                               const __half* __restrict__ xh,
                                               float* __restrict__ agg) {
    int n = blockIdx.x;
    int hf = threadIdx.x >> 6;
    int lane = threadIdx.x & 63;
    int s = offs[n], e = offs[n + 1];
    const __half* b0 = xh + (size_t)(2 * hf) * NN * DD + lane * 2;
    const __half* b1 = xh + (size_t)(2 * hf + 1) * NN * DD + lane * 2;
    float a00 = 0.f, a01 = 0.f, a10 = 0.f, a11 = 0.f;
    #pragma unroll 2
    for (int p = s; p < e; p++) {
        int2 cw = cpack[p];
        int c = cw.x;
        float wv = __int_as_float(cw.y);
        float2 f0 = __half22float2(*reinterpret_cast<const __half2*>(b0 + (size_t)c * DD));
        float2 f1 = __half22float2(*reinterpret_cast<const __half2*>(b1 + (size_t)c * DD));
        a00 += wv * f0.x; a01 += wv * f0.y;
        a10 += wv * f1.x; a11 += wv * f1.y;
    }
    *reinterpret_cast<float2*>(agg + ((size_t)(2 * hf) * NN + n) * DD + lane * 2)     = make_float2(a00, a01);
    *reinterpret_cast<float2*>(agg + ((size_t)(2 * hf + 1) * NN + n) * DD + lane * 2) = make_float2(a10, a11);
}

// ---------- fallback f32 gather (small workspace) ----------
__global__ __launch_bounds__(128) void k_agg_f(const int* __restrict__ offs,
                                               const int2* __restrict__ cpack,
                                               const float* __restrict__ x,
                                               float* __restrict__ agg) {
    int n = blockIdx.x;
    int tid = threadIdx.x;    // = d
    int s = offs[n], e = offs[n + 1];
    float a0 = 0.f, a1 = 0.f, a2 = 0.f, a3 = 0.f;
    for (int p = s; p < e; p++) {
        int2 cw = cpack[p];
        int c = cw.x;
        float w = __int_as_float(cw.y);
        a0 += w * x[((size_t)(0 * NN + c)) * DD + tid];
        a1 += w * x[((size_t)(1 * NN + c)) * DD + tid];
        a2 += w * x[((size_t)(2 * NN + c)) * DD + tid];
        a3 += w * x[((size_t)(3 * NN + c)) * DD + tid];
    }
    agg[((size_t)(0 * NN + n)) * DD + tid] = a0;
    agg[((size_t)(1 * NN + n)) * DD + tid] = a1;
    agg[((size_t)(2 * NN + n)) * DD + tid] = a2;
    agg[((size_t)(3 * NN + n)) * DD + tid] = a3;
}

// ---------- weight prep: transpose + bf16 hi/lo split ----------
// out layout (shorts): sWh[16384] sWl | aWh aWl | vWh vWl | l1h[32768] l1l | l2h l2l | kqh[4096] kql
__global__ void k_wprep(const float* __restrict__ sW, const float* __restrict__ aW,
                        const float* __restrict__ vW, const float* __restrict__ w1,
                        const float* __restrict__ w2,
                        const float* __restrict__ wk, const float* __restrict__ wq,
                        short* __restrict__ out) {
    int b = blockIdx.x;   // 400 blocks x 256 threads
    if (b < 384) {
        const float* src; short* h; short* l; int K; int base;
        if (b < 64)       { src = sW; h = out;          l = out + 16384;  K = 128; base = b; }
        else if (b < 128) { src = aW; h = out + 32768;  l = out + 49152;  K = 128; base = b - 64; }
        else if (b < 192) { src = vW; h = out + 65536;  l = out + 81920;  K = 128; base = b - 128; }
        else if (b < 320) { src = w1; h = out + 98304;  l = out + 131072; K = 256; base = b - 192; }
        else              { src = w2; h = out + 163840; l = out + 180224; K = 128; base = b - 320; }
        int idx = base * 256 + threadIdx.x;   // over K*128, row-major [K][128]
        int k = idx >> 7, n = idx & 127;
        float v = src[idx];
        short hh = f2bf(v);
        h[n * K + k] = hh;                    // transposed: [n][K]
        l[n * K + k] = f2bf(v - bf2f(hh));
    } else {
        // kq: cols 0..15 = Wk^T, 16..31 = Wq^T, layout [32][128]
        int idx = (b - 384) * 256 + threadIdx.x;   // < 4096
        int j = idx >> 7, k = idx & 127;
        float v = (j < 16) ? wk[k * KDIM + j] : wq[k * KDIM + (j - 16)];
        short hh = f2bf(v);
        out[196608 + j * 128 + k] = hh;
        out[200704 + j * 128 + k] = f2bf(v - bf2f(hh));
    }
}

// ---------- stage 64x128 f32 rows -> LDS bf16 hi/lo tiles, row stride 136 ----------
__device__ __forceinline__ void stage64(const float* __restrict__ src, int rowbase,
                                        short* __restrict__ h, short* __restrict__ l, int tid) {
    int row = tid >> 2, ko = (tid & 3) * 32;
    const float* gp = src + (size_t)(rowbase + row) * DD + ko;
    short* dh = h + row * 136 + ko;
    short* dl = l + row * 136 + ko;
    #pragma unroll
    for (int j = 0; j < 4; j++) {
        float4 a = *reinterpret_cast<const float4*>(gp + j * 8);
        float4 b = *reinterpret_cast<const float4*>(gp + j * 8 + 4);
        float v[8] = {a.x, a.y, a.z, a.w, b.x, b.y, b.z, b.w};
        s16x8 hv, lv;
        #pragma unroll
        for (int e = 0; e < 8; e++) {
            short hh = f2bf(v[e]);
            hv[e] = hh;
            lv[e] = f2bf(v[e] - bf2f(hh));
        }
        *(s16x8*)(dh + j * 8) = hv;
        *(s16x8*)(dl + j * 8) = lv;
    }
}

// ---------- 64x128 GEMM pass, K=128, bf16x3 split MFMA (A hi+lo) ----------
// A (hi/lo) in LDS [64][136]; B = W^T (hi/lo) in global [128][wlen], k-offset koff.
// C/D layout [m89]: col = lane&15, row = (lane>>4)*4 + reg.
__device__ __forceinline__ void mfma_pass(const short* __restrict__ a0, const short* __restrict__ a1,
                                          const short* __restrict__ Wh, const short* __restrict__ Wl,
                                          int wlen, int koff, int w, int l16, int kg,
                                          fx4 acc[4][2]) {
    #pragma unroll
    for (int ks = 0; ks < 4; ks++) {
        s16x8 ah[4], al[4];
        #pragma unroll
        for (int mt = 0; mt < 4; mt++) {
            int ao = (mt * 16 + l16) * 136 + ks * 32 + kg * 8;
            ah[mt] = *(const s16x8*)(a0 + ao);
            al[mt] = *(const s16x8*)(a1 + ao);
        }
        #pragma unroll
        for (int nt = 0; nt < 2; nt++) {
            int col = w * 32 + nt * 16 + l16;
            int bo = col * wlen + koff + ks * 32 + kg * 8;
            s16x8 bh = *(const s16x8*)(Wh + bo);
            s16x8 bl = *(const s16x8*)(Wl + bo);
            #pragma unroll
            for (int mt = 0; mt < 4; mt++) {
                acc[mt][nt] = __builtin_amdgcn_mfma_f32_16x16x32_bf16(ah[mt], bh, acc[mt][nt], 0, 0, 0);
                acc[mt][nt] = __builtin_amdgcn_mfma_f32_16x16x32_bf16(ah[mt], bl, acc[mt][nt], 0, 0, 0);
                acc[mt][nt] = __builtin_amdgcn_mfma_f32_16x16x32_bf16(al[mt], bh, acc[mt][nt], 0, 0, 0);
            }
        }
    }
}

// ---------- 2-term variant: A is single-plane bf16 (LN output), B keeps hi+lo ----------
__device__ __forceinline__ void mfma_pass_hi(const short* __restrict__ a0,
                                             const short* __restrict__ Wh, const short* __restrict__ Wl,
                                             int wlen, int koff, int w, int l16, int kg,
                                             fx4 acc[4][2]) {
    #pragma unroll
    for (int ks = 0; ks < 4; ks++) {
        s16x8 ah[4];
        #pragma unroll
        for (int mt = 0; mt < 4; mt++)
            ah[mt] = *(const s16x8*)(a0 + (mt * 16 + l16) * 136 + ks * 32 + kg * 8);
        #pragma unroll
        for (int nt = 0; nt < 2; nt++) {
            int col = w * 32 + nt * 16 + l16;
            int bo = col * wlen + koff + ks * 32 + kg * 8;
            s16x8 bh = *(const s16x8*)(Wh + bo);
            s16x8 bl = *(const s16x8*)(Wl + bo);
            #pragma unroll
            for (int mt = 0; mt < 4; mt++) {
                acc[mt][nt] = __builtin_amdgcn_mfma_f32_16x16x32_bf16(ah[mt], bh, acc[mt][nt], 0, 0, 0);
                acc[mt][nt] = __builtin_amdgcn_mfma_f32_16x16x32_bf16(ah[mt], bl, acc[mt][nt], 0, 0, 0);
            }
        }
    }
}

// ---------- sage GEMMs + kq piggyback: io = LN(silu(agg@aggW + x@sageW + b)), wt = mean(k*q) ----------
__global__ __launch_bounds__(256, 4) void k_sage2(
    const float* __restrict__ x,
    const short* __restrict__ aWh, const short* __restrict__ aWl,
    const short* __restrict__ sWh, const short* __restrict__ sWl,
    const short* __restrict__ kqh, const short* __restrict__ kql,
    const float* __restrict__ bias, const float* __restrict__ g, const float* __restrict__ bb,
    float* __restrict__ wt_total, float* __restrict__ iw0,
    float* __restrict__ io) {
    __shared__ __align__(16) short stg[2][64 * 136];   // 34816 B; f32 LN scratch aliases
    float* fscr = (float*)&stg[0][0];
    short* sh = &stg[0][0];
    short* sl = &stg[1][0];
    const int rowbase = blockIdx.x * 64;
    const int tid = threadIdx.x;
    const int w = tid >> 6, lane = tid & 63;
    const int l16 = lane & 15, kg = lane >> 4;

    fx4 acc[4][2];
    #pragma unroll
    for (int mt = 0; mt < 4; mt++)
        #pragma unroll
        for (int nt = 0; nt < 2; nt++) acc[mt][nt] = (fx4){0.f, 0.f, 0.f, 0.f};

    // ---- agg tile (from io) @ aggW ----
    stage64(io, rowbase, sh, sl, tid);
    __syncthreads();
    mfma_pass(sh, sl, aWh, aWl, 128, 0, w, l16, kg, acc);
    __syncthreads();

    // ---- x tile @ sageW + kq piggyback ----
    stage64(x, rowbase, sh, sl, tid);
    __syncthreads();
    mfma_pass(sh, sl, sWh, sWl, 128, 0, w, l16, kg, acc);

    fx4 acck[2];
    acck[0] = (fx4){0.f, 0.f, 0.f, 0.f};
    acck[1] = (fx4){0.f, 0.f, 0.f, 0.f};
    #pragma unroll
    for (int ks = 0; ks < 4; ks++) {
        int ao = (w * 16 + l16) * 136 + ks * 32 + kg * 8;
        s16x8 ah = *(const s16x8*)(sh + ao);
        s16x8 al = *(const s16x8*)(sl + ao);
        #pragma unroll
        for (int nt = 0; nt < 2; nt++) {
            int bo = (nt * 16 + l16) * 128 + ks * 32 + kg * 8;
            s16x8 bh = *(const s16x8*)(kqh + bo);
            s16x8 bl = *(const s16x8*)(kql + bo);
            acck[nt] = __builtin_amdgcn_mfma_f32_16x16x32_bf16(ah, bh, acck[nt], 0, 0, 0);
            acck[nt] = __builtin_amdgcn_mfma_f32_16x16x32_bf16(ah, bl, acck[nt], 0, 0, 0);
            acck[nt] = __builtin_amdgcn_mfma_f32_16x16x32_bf16(al, bh, acck[nt], 0, 0, 0);
        }
    }
    #pragma unroll
    for (int r = 0; r < 4; r++) {
        float pr = acck[0][r] * acck[1][r];
        pr += __shfl_xor(pr, 1, 64);
        pr += __shfl_xor(pr, 2, 64);
        pr += __shfl_xor(pr, 4, 64);
        pr += __shfl_xor(pr, 8, 64);
        if (l16 == 0) {
            int row = w * 16 + kg * 4 + r;
            int m = rowbase + row;
            int l = m / NN, n = m - l * NN;
            float sv = pr * (1.f / 16.f);
            wt_total[n * LL + l] = sv;
            iw0[n * LL + l] = sv;
        }
    }
    __syncthreads();   // all LDS reads done before fscr overwrite

    // ---- epilogue: +bias, silu -> fscr; LN -> io ----
    float bias_r[2];
    #pragma unroll
    for (int nt = 0; nt < 2; nt++) bias_r[nt] = bias[w * 32 + nt * 16 + l16];
    #pragma unroll
    for (int mt = 0; mt < 4; mt++) {
        #pragma unroll
        for (int r = 0; r < 4; r++) {
            int row = mt * 16 + kg * 4 + r;
            #pragma unroll
            for (int nt = 0; nt < 2; nt++) {
                int col = w * 32 + nt * 16 + l16;
                fscr[row * 129 + col] = silu(acc[mt][nt][r] + bias_r[nt]);
            }
        }
    }
    __syncthreads();
    {
        float g0 = g[lane], g1 = g[64 + lane];
        float b0 = bb[lane], b1 = bb[64 + lane];
        #pragma unroll 1
        for (int rr = 0; rr < 16; rr++) {
            int row = w * 16 + rr;
            size_t m = (size_t)rowbase + row;
            float y0 = fscr[row * 129 + lane], y1 = fscr[row * 129 + 64 + lane];
            float s = y0 + y1, q = y0 * y0 + y1 * y1;
            #pragma unroll
            for (int off = 32; off; off >>= 1) {
                s += __shfl_xor(s, off, 64);
                q += __shfl_xor(q, off, 64);
            }
            float mean = s * (1.f / 128.f);
            float var = fmaxf(q * (1.f / 128.f) - mean * mean, 0.f);
            float rstd = rsqrtf(var + EPSF);
            io[m * DD + lane]      = (y0 - mean) * rstd * g0 + b0;
            io[m * DD + 64 + lane] = (y1 - mean) * rstd * g1 + b1;
        }
    }
}

// ---------- fused lin1 + lin2: att branch, h1 (LDS only), out = LN2(silu(h1@W2 + b2 + x)) ----------
// atl is SINGLE-plane bf16 (LN outputs, O(1)): halves LDS -> 3 blocks/CU, and W1b/W2
// passes use the 2-term split (A-hi x B-hi + A-hi x B-lo).
__global__ __launch_bounds__(256, 3) void k_lin12(
    const float* __restrict__ x,
    const short* __restrict__ Wvh, const short* __restrict__ Wvl,
    const float* __restrict__ wtbuf,
    const float* __restrict__ att_g, const float* __restrict__ att_b,
    const short* __restrict__ W1h, const short* __restrict__ W1l,   // [128][256] transposed
    const float* __restrict__ b1v,
    const float* __restrict__ ln1g, const float* __restrict__ ln1b,
    const short* __restrict__ W2h, const short* __restrict__ W2l,   // [128][128] transposed
    const float* __restrict__ b2v,
    const float* __restrict__ ln2g, const float* __restrict__ ln2b,
    float* __restrict__ io) {                                        // sage in, out in-place
    __shared__ __align__(16) short stg[2][64 * 136];   // staging hi/lo + f32 LN scratch alias (34816 B)
    __shared__ __align__(16) short atl[64 * 136];      // att-LN / h1-LN bf16 tile (17408 B)
    float* fscr = (float*)&stg[0][0];
    const int rowbase = blockIdx.x * 64;
    const int tid = threadIdx.x;
    const int w = tid >> 6, lane = tid & 63;
    const int l16 = lane & 15, kg = lane >> 4;

    // T14: issue sage loads now; consumed at restage much later.
    float4 pf[8];
    {
        int row = tid >> 2, ko = (tid & 3) * 32;
        const float* gp = io + (size_t)(rowbase + row) * DD + ko;
        #pragma unroll
        for (int j = 0; j < 8; j++) pf[j] = *reinterpret_cast<const float4*>(gp + j * 4);
    }

    fx4 acc[4][2];
    #pragma unroll
    for (int mt = 0; mt < 4; mt++)
        #pragma unroll
        for (int nt = 0; nt < 2; nt++) acc[mt][nt] = (fx4){0.f, 0.f, 0.f, 0.f};

    // ---- att: x @ Wv ----
    stage64(x, rowbase, &stg[0][0], &stg[1][0], tid);
    __syncthreads();
    mfma_pass(&stg[0][0], &stg[1][0], Wvh, Wvl, 128, 0, w, l16, kg, acc);
    __syncthreads();

    #pragma unroll
    for (int mt = 0; mt < 4; mt++) {
        #pragma unroll
        for (int r = 0; r < 4; r++) {
            int row = mt * 16 + kg * 4 + r;
            int m = rowbase + row;
            int l = m / NN, n = m - l * NN;
            float ws = wtbuf[n * LL + l];
            #pragma unroll
            for (int nt = 0; nt < 2; nt++) {
                int col = w * 32 + nt * 16 + l16;
                fscr[row * 129 + col] = acc[mt][nt][r] * ws;
            }
        }
    }
    __syncthreads();
    {   // att LN -> atl (bf16 hi only)
        float g0 = att_g[lane], g1 = att_g[64 + lane];
        float b0 = att_b[lane], b1 = att_b[64 + lane];
        #pragma unroll 1
        for (int rr = 0; rr < 16; rr++) {
            int row = w * 16 + rr;
            float y0 = fscr[row * 129 + lane], y1 = fscr[row * 129 + 64 + lane];
            float s = y0 + y1, q = y0 * y0 + y1 * y1;
            #pragma unroll
            for (int off = 32; off; off >>= 1) {
                s += __shfl_xor(s, off, 64);
                q += __shfl_xor(q, off, 64);
            }
            float mean = s * (1.f / 128.f);
            float var = fmaxf(q * (1.f / 128.f) - mean * mean, 0.f);
            float rstd = rsqrtf(var + EPSF);
            atl[row * 136 + lane]      = f2bf((y0 - mean) * rstd * g0 + b0);
            atl[row * 136 + 64 + lane] = f2bf((y1 - mean) * rstd * g1 + b1);
        }
    }
    __syncthreads();

    // ---- restage sage tile from prefetched regs ----
    {
        int row = tid >> 2, ko = (tid & 3) * 32;
        short* dh = &stg[0][0] + row * 136 + ko;
        short* dl = &stg[1][0] + row * 136 + ko;
        #pragma unroll
        for (int j = 0; j < 4; j++) {
            float v[8] = {pf[2 * j].x, pf[2 * j].y, pf[2 * j].z, pf[2 * j].w,
                          pf[2 * j + 1].x, pf[2 * j + 1].y, pf[2 * j + 1].z, pf[2 * j + 1].w};
            s16x8 hv, lv;
            #pragma unroll
            for (int e = 0; e < 8; e++) {
                short hh = f2bf(v[e]);
                hv[e] = hh;
                lv[e] = f2bf(v[e] - bf2f(hh));
            }
            *(s16x8*)(dh + j * 8) = hv;
            *(s16x8*)(dl + j * 8) = lv;
        }
    }
    #pragma unroll
    for (int mt = 0; mt < 4; mt++)
        #pragma unroll
        for (int nt = 0; nt < 2; nt++) acc[mt][nt] = (fx4){0.f, 0.f, 0.f, 0.f};
    __syncthreads();

    // ---- h1 = sage @ W1[:,0:128] + atile @ W1[:,128:256] ----
    mfma_pass(&stg[0][0], &stg[1][0], W1h, W1l, 256, 0, w, l16, kg, acc);
    mfma_pass_hi(atl, W1h, W1l, 256, 128, w, l16, kg, acc);
    __syncthreads();

    {   // bias + silu -> fscr
        float bias_r[2];
        #pragma unroll
        for (int nt = 0; nt < 2; nt++) bias_r[nt] = b1v[w * 32 + nt * 16 + l16];
        #pragma unroll
        for (int mt = 0; mt < 4; mt++) {
            #pragma unroll
            for (int r = 0; r < 4; r++) {
                int row = mt * 16 + kg * 4 + r;
                #pragma unroll
                for (int nt = 0; nt < 2; nt++) {
                    int col = w * 32 + nt * 16 + l16;
                    fscr[row * 129 + col] = silu(acc[mt][nt][r] + bias_r[nt]);
                }
            }
        }
    }
    __syncthreads();
    {   // LN1 -> atl (bf16 hi only), h1 stays on-chip
        float g0 = ln1g[lane], g1 = ln1g[64 + lane];
        float b0 = ln1b[lane], b1 = ln1b[64 + lane];
        #pragma unroll 1
        for (int rr = 0; rr < 16; rr++) {
            int row = w * 16 + rr;
            float y0 = fscr[row * 129 + lane], y1 = fscr[row * 129 + 64 + lane];
            float s = y0 + y1, q = y0 * y0 + y1 * y1;
            #pragma unroll
            for (int off = 32; off; off >>= 1) {
                s += __shfl_xor(s, off, 64);
                q += __shfl_xor(q, off, 64);
            }
            float mean = s * (1.f / 128.f);
            float var = fmaxf(q * (1.f / 128.f) - mean * mean, 0.f);
            float rstd = rsqrtf(var + EPSF);
            atl[row * 136 + lane]      = f2bf((y0 - mean) * rstd * g0 + b0);
            atl[row * 136 + 64 + lane] = f2bf((y1 - mean) * rstd * g1 + b1);
        }
    }
    __syncthreads();

    // ---- out = LN2(silu(h1 @ W2 + b2 + x)) ----
    #pragma unroll
    for (int mt = 0; mt < 4; mt++)
        #pragma unroll
        for (int nt = 0; nt < 2; nt++) acc[mt][nt] = (fx4){0.f, 0.f, 0.f, 0.f};
    mfma_pass_hi(atl, W2h, W2l, 128, 0, w, l16, kg, acc);
    {
        float bias_r[2];
        #pragma unroll
        for (int nt = 0; nt < 2; nt++) bias_r[nt] = b2v[w * 32 + nt * 16 + l16];
        #pragma unroll
        for (int mt = 0; mt < 4; mt++) {
            #pragma unroll
            for (int r = 0; r < 4; r++) {
                int row = mt * 16 + kg * 4 + r;
                size_t m = (size_t)rowbase + row;
                #pragma unroll
                for (int nt = 0; nt < 2; nt++) {
                    int col = w * 32 + nt * 16 + l16;
                    fscr[row * 129 + col] = silu(acc[mt][nt][r] + bias_r[nt] + x[m * DD + col]);
                }
            }
        }
    }
    __syncthreads();
    {
        float g0 = ln2g[lane], g1 = ln2g[64 + lane];
        float b0 = ln2b[lane], b1 = ln2b[64 + lane];
        #pragma unroll 1
        for (int rr = 0; rr < 16; rr++) {
            int row = w * 16 + rr;
            size_t m = (size_t)rowbase + row;
            float y0 = fscr[row * 129 + lane], y1 = fscr[row * 129 + 64 + lane];
            float s = y0 + y1, q = y0 * y0 + y1 * y1;
            #pragma unroll
            for (int off = 32; off; off >>= 1) {
                s += __shfl_xor(s, off, 64);
                q += __shfl_xor(q, off, 64);
            }
            float mean = s * (1.f / 128.f);
            float var = fmaxf(q * (1.f / 128.f) - mean * mean, 0.f);
            float rstd = rsqrtf(var + EPSF);
            io[m * DD + lane]      = (y0 - mean) * rstd * g0 + b0;
            io[m * DD + 64 + lane] = (y1 - mean) * rstd * g1 + b1;
        }
    }
}

// ---------- retentive weight iteration (f32 vals — sign-critical) ----------
__global__ __launch_bounds__(256) void k_spmm_w(const int* __restrict__ offs,
                                                const int2* __restrict__ cpack,
                                                const float* __restrict__ win, float* __restrict__ wout,
                                                float* __restrict__ wtot) {
    int i = blockIdx.x * 256 + threadIdx.x;
    if (i >= NN * LL) return;
    int n = i >> 2, l = i & 3;
    int s = offs[n], e = offs[n + 1];
    float a = 0.f;
    for (int p = s; p < e; p++) {
        int2 cw = cpack[p];
        a += __int_as_float(cw.y) * win[(cw.x << 2) | l];
    }
    a *= DECAYF;
    wout[i] = a;
    wtot[i] += a;
}

extern "C" void kernel_launch(void* const* d_in, const int* in_sizes, int n_in,
                              void* d_out, int out_size, void* d_ws, size_t ws_size,
                              hipStream_t stream) {
    const float* x        = (const float*)d_in[0];
    const int*   ei       = (const int*)d_in[1];
    const float* evals    = (const float*)d_in[2];
    const float* sage_W   = (const float*)d_in[3];
    const float* sage_b   = (const float*)d_in[4];
    const float* sage_aggW= (const float*)d_in[5];
    const float* sage_ln_g= (const float*)d_in[6];
    const float* sage_ln_b= (const float*)d_in[7];
    const float* att_Wk   = (const float*)d_in[8];
    const float* att_Wq   = (const float*)d_in[9];
    const float* att_Wv   = (const float*)d_in[10];
    const float* att_ln_g = (const float*)d_in[11];
    const float* att_ln_b = (const float*)d_in[12];
    const float* lin1_W   = (const float*)d_in[13];
    const float* lin1_b   = (const float*)d_in[14];
    const float* lin2_W   = (const float*)d_in[15];
    const float* lin2_b   = (const float*)d_in[16];
    const float* ln1_g    = (const float*)d_in[17];
    const float* ln1_b    = (const float*)d_in[18];
    const float* ln2_g    = (const float*)d_in[19];
    const float* ln2_b    = (const float*)d_in[20];

    const int* rows = ei;
    const int* cols = ei + EE;

    // ---- workspace layout ----
    float* wt_total = (float*)d_ws;                       // [M]
    float* iw0      = wt_total + MM;
    float* iw1      = iw0 + MM;
    int*   counts   = (int*)(iw1 + MM);                   // N
    int*   offs     = counts + NN;                        // N+1
    int*   cursor   = offs + NN + 1;                      // N
    int*   csum     = cursor + NN;                        // 128
    uintptr_t pc    = (uintptr_t)(csum + 128);
    pc = (pc + 15) & ~(uintptr_t)15;
    int2*  cpack    = (int2*)pc;                          // E (col, f32 valbits)
    uintptr_t pw    = (uintptr_t)(cpack + EE);
    pw = (pw + 15) & ~(uintptr_t)15;
    short* wbf      = (short*)pw;                         // 204800 shorts
    uintptr_t ph    = (uintptr_t)(wbf + 204800);
    ph = (ph + 255) & ~(uintptr_t)255;
    __half* xh      = (__half*)ph;                        // M*D fp16 = 51.2 MB (optional)
    size_t need_h   = (ph - (uintptr_t)d_ws) + (size_t)MM * DD * sizeof(__half);
    bool use_half   = ws_size >= need_h;
    float* io       = (float*)d_out;                      // [M,D] f32: agg -> sage -> out

    // ---- weight transpose+split ----
    k_wprep<<<400, 256, 0, stream>>>(sage_W, sage_aggW, att_Wv, lin1_W, lin2_W,
                                     att_Wk, att_Wq, wbf);

    // ---- CSR build ----
    k_zero<<<(NN + 255) / 256, 256, 0, stream>>>(counts, NN);
    k_hist<<<(EE + 255) / 256, 256, 0, stream>>>(rows, counts);
    k_scan1<<<SCAN_NBLK, SCAN_CHUNK, 0, stream>>>(counts, offs, csum);
    k_scan2<<<1, 128, 0, stream>>>(csum);
    k_scan3<<<SCAN_NBLK, SCAN_CHUNK, 0, stream>>>(offs, csum, cursor);
    k_fill<<<(EE + 255) / 256, 256, 0, stream>>>(rows, cols, evals, cursor, cpack);

    // ---- SAGE aggregation -> io ----
    if (use_half) {
        k_xhalf<<<(MM * DD / 4 + 255) / 256, 256, 0, stream>>>(x, xh);
        k_agg_h<<<NN, 128, 0, stream>>>(offs, cpack, xh, io);
    } else {
        k_agg_f<<<NN, 128, 0, stream>>>(offs, cpack, x, io);
    }

    // ---- sage GEMMs + kq -> io in-place, wt_total/iw0 ----
    k_sage2<<<MM / 64, 256, 0, stream>>>(
        x,
        wbf + 32768, wbf + 49152,      // aggW
        wbf, wbf + 16384,              // sageW
        wbf + 196608, wbf + 200704,    // kq
        sage_b, sage_ln_g, sage_ln_b,
        wt_total, iw0, io);

    // ---- retentive weight iterations ----
    k_spmm_w<<<(MM + 255) / 256, 256, 0, stream>>>(offs, cpack, iw0, iw1, wt_total);
    k_spmm_w<<<(MM + 255) / 256, 256, 0, stream>>>(offs, cpack, iw1, iw0, wt_total);

    // ---- fused lin1+lin2 -> io (= d_out) in-place ----
    k_lin12<<<MM / 64, 256, 0, stream>>>(
        x, wbf + 65536, wbf + 81920, wt_total, att_ln_g, att_ln_b,
        wbf + 98304, wbf + 131072, lin1_b, ln1_g, ln1_b,
        wbf + 163840, wbf + 180224, lin2_b, ln2_g, ln2_b,
        io);

    (void)in_sizes; (void)n_in; (void)out_size;
}

// Round 6
// 700.874 us; speedup vs baseline: 1.8010x; 1.1002x over previous
//
#include <hip/hip_runtime.h>
#include <hip/hip_fp16.h>

#define NN 50000
#define LL 4
#define DD 128
#define KDIM 16
#define EE 800000
#define MM (NN * LL)
#define DECAYF 0.7f
#define EPSF 1e-5f
#define SCAN_CHUNK 512
#define SCAN_NBLK ((NN + SCAN_CHUNK - 1) / SCAN_CHUNK)   // 98

typedef __attribute__((ext_vector_type(8))) short s16x8;   // 8 bf16 (4 VGPRs) MFMA frag
typedef __attribute__((ext_vector_type(4))) float fx4;     // MFMA accumulator

// ---------- bf16 helpers (RNE) ----------
__device__ __forceinline__ short f2bf(float x) {
    unsigned u = __float_as_uint(x);
    u += 0x7fffu + ((u >> 16) & 1u);
    return (short)(u >> 16);
}
__device__ __forceinline__ float bf2f(short h) {
    return __uint_as_float(((unsigned)(unsigned short)h) << 16);
}
// fast silu: y * rcp(1+exp(-y)); error ~1e-7
__device__ __forceinline__ float silu(float y) {
    return y * __builtin_amdgcn_rcpf(1.f + __expf(-y));
}

// ---------- CSR build ----------
__global__ void k_zero(int* p, int n) {
    int i = blockIdx.x * 256 + threadIdx.x;
    if (i < n) p[i] = 0;
}
__global__ void k_hist(const int* __restrict__ rows, int* __restrict__ counts) {
    int e = blockIdx.x * 256 + threadIdx.x;
    if (e < EE) atomicAdd(&counts[rows[e]], 1);
}
__global__ void k_scan1(const int* __restrict__ counts, int* __restrict__ offs, int* __restrict__ csum) {
    __shared__ int s[SCAN_CHUNK];
    int i = blockIdx.x * SCAN_CHUNK + threadIdx.x;
    int v = (i < NN) ? counts[i] : 0;
    s[threadIdx.x] = v;
    __syncthreads();
    for (int off = 1; off < SCAN_CHUNK; off <<= 1) {
        int t = (threadIdx.x >= off) ? s[threadIdx.x - off] : 0;
        __syncthreads();
        s[threadIdx.x] += t;
        __syncthreads();
    }
    if (i < NN) offs[i] = s[threadIdx.x] - v;
    if (threadIdx.x == SCAN_CHUNK - 1) csum[blockIdx.x] = s[SCAN_CHUNK - 1];
}
__global__ void k_scan2(int* __restrict__ csum) {
    __shared__ int s[128];
    int v = (threadIdx.x < SCAN_NBLK) ? csum[threadIdx.x] : 0;
    s[threadIdx.x] = v;
    __syncthreads();
    for (int off = 1; off < 128; off <<= 1) {
        int t = (threadIdx.x >= off) ? s[threadIdx.x - off] : 0;
        __syncthreads();
        s[threadIdx.x] += t;
        __syncthreads();
    }
    if (threadIdx.x < SCAN_NBLK) csum[threadIdx.x] = s[threadIdx.x] - v;
}
__global__ void k_scan3(int* __restrict__ offs, const int* __restrict__ csum, int* __restrict__ cursor) {
    int i = blockIdx.x * SCAN_CHUNK + threadIdx.x;
    if (i < NN) {
        int v = offs[i] + csum[blockIdx.x];
        offs[i] = v;
        cursor[i] = v;
    } else if (i == NN) {
        offs[NN] = EE;
    }
}
// pack: (col, f32 val) — f32 vals REQUIRED: retentive-weight path is sign-sensitive
// (LN cancels |w|); fp16 vals flip signs of near-zero weights (round-3 failure).
__global__ void k_fill(const int* __restrict__ rows, const int* __restrict__ cols,
                       const float* __restrict__ vals,
                       int* __restrict__ cursor, int2* __restrict__ cpack) {
    int e = blockIdx.x * 256 + threadIdx.x;
    if (e < EE) {
        int r = rows[e];
        int pos = atomicAdd(&cursor[r], 1);
        cpack[pos] = make_int2(cols[e], __float_as_int(vals[e]));
    }
}

// ---------- x f32 -> fp16 ----------
__global__ __launch_bounds__(256) void k_xhalf(const float* __restrict__ x, __half* __restrict__ xh) {
    size_t i = (size_t)blockIdx.x * 256 + threadIdx.x;   // over M*D/4 = 6.4M
    float4 v = *reinterpret_cast<const float4*>(x + i * 4);
    __half2 h0 = __floats2half2_rn(v.x, v.y);
    __half2 h1 = __floats2half2_rn(v.z, v.w);
    __half2* d = reinterpret_cast<__half2*>(xh + i * 4);
    d[0] = h0;
    d[1] = h1;
}

// ---------- SAGE aggregation (fp16 x gather, f32 vals/accum) -> agg f32 ----------
__global__ __launch_bounds__(128) void k_agg_h(const int* __restrict__ offs,
                                               const int2* __restrict__ cpack,
                                               const __half* __restrict__ xh,
                                               float* __restrict__ agg) {
    int n = blockIdx.x;
    int hf = threadIdx.x >> 6;
    int lane = threadIdx.x & 63;
    int s = offs[n], e = offs[n + 1];
    const __half* b0 = xh + (size_t)(2 * hf) * NN * DD + lane * 2;
    const __half* b1 = xh + (size_t)(2 * hf + 1) * NN * DD + lane * 2;
    float a00 = 0.f, a01 = 0.f, a10 = 0.f, a11 = 0.f;
    #pragma unroll 2
    for (int p = s; p < e; p++) {
        int2 cw = cpack[p];
        int c = cw.x;
        float wv = __int_as_float(cw.y);
        float2 f0 = __half22float2(*reinterpret_cast<const __half2*>(b0 + (size_t)c * DD));
        float2 f1 = __half22float2(*reinterpret_cast<const __half2*>(b1 + (size_t)c * DD));
        a00 += wv * f0.x; a01 += wv * f0.y;
        a10 += wv * f1.x; a11 += wv * f1.y;
    }
    *reinterpret_cast<float2*>(agg + ((size_t)(2 * hf) * NN + n) * DD + lane * 2)     = make_float2(a00, a01);
    *reinterpret_cast<float2*>(agg + ((size_t)(2 * hf + 1) * NN + n) * DD + lane * 2) = make_float2(a10, a11);
}

// ---------- fallback f32 gather (small workspace) ----------
__global__ __launch_bounds__(128) void k_agg_f(const int* __restrict__ offs,
                                               const int2* __restrict__ cpack,
                                               const float* __restrict__ x,
                                               float* __restrict__ agg) {
    int n = blockIdx.x;
    int tid = threadIdx.x;    // = d
    int s = offs[n], e = offs[n + 1];
    float a0 = 0.f, a1 = 0.f, a2 = 0.f, a3 = 0.f;
    for (int p = s; p < e; p++) {
        int2 cw = cpack[p];
        int c = cw.x;
        float w = __int_as_float(cw.y);
        a0 += w * x[((size_t)(0 * NN + c)) * DD + tid];
        a1 += w * x[((size_t)(1 * NN + c)) * DD + tid];
        a2 += w * x[((size_t)(2 * NN + c)) * DD + tid];
        a3 += w * x[((size_t)(3 * NN + c)) * DD + tid];
    }
    agg[((size_t)(0 * NN + n)) * DD + tid] = a0;
    agg[((size_t)(1 * NN + n)) * DD + tid] = a1;
    agg[((size_t)(2 * NN + n)) * DD + tid] = a2;
    agg[((size_t)(3 * NN + n)) * DD + tid] = a3;
}

// ---------- weight prep: transpose + bf16 hi/lo split ----------
// out layout (shorts): sWh[16384] sWl | aWh aWl | vWh vWl | l1h[32768] l1l | l2h l2l | kqh[4096] kql
__global__ void k_wprep(const float* __restrict__ sW, const float* __restrict__ aW,
                        const float* __restrict__ vW, const float* __restrict__ w1,
                        const float* __restrict__ w2,
                        const float* __restrict__ wk, const float* __restrict__ wq,
                        short* __restrict__ out) {
    int b = blockIdx.x;   // 400 blocks x 256 threads
    if (b < 384) {
        const float* src; short* h; short* l; int K; int base;
        if (b < 64)       { src = sW; h = out;          l = out + 16384;  K = 128; base = b; }
        else if (b < 128) { src = aW; h = out + 32768;  l = out + 49152;  K = 128; base = b - 64; }
        else if (b < 192) { src = vW; h = out + 65536;  l = out + 81920;  K = 128; base = b - 128; }
        else if (b < 320) { src = w1; h = out + 98304;  l = out + 131072; K = 256; base = b - 192; }
        else              { src = w2; h = out + 163840; l = out + 180224; K = 128; base = b - 320; }
        int idx = base * 256 + threadIdx.x;   // over K*128, row-major [K][128]
        int k = idx >> 7, n = idx & 127;
        float v = src[idx];
        short hh = f2bf(v);
        h[n * K + k] = hh;                    // transposed: [n][K]
        l[n * K + k] = f2bf(v - bf2f(hh));
    } else {
        // kq: cols 0..15 = Wk^T, 16..31 = Wq^T, layout [32][128]
        int idx = (b - 384) * 256 + threadIdx.x;   // < 4096
        int j = idx >> 7, k = idx & 127;
        float v = (j < 16) ? wk[k * KDIM + j] : wq[k * KDIM + (j - 16)];
        short hh = f2bf(v);
        out[196608 + j * 128 + k] = hh;
        out[200704 + j * 128 + k] = f2bf(v - bf2f(hh));
    }
}

// ---------- stage 64x128 f32 rows -> LDS bf16 hi/lo tiles, row stride 136 ----------
__device__ __forceinline__ void stage64(const float* __restrict__ src, int rowbase,
                                        short* __restrict__ h, short* __restrict__ l, int tid) {
    int row = tid >> 2, ko = (tid & 3) * 32;
    const float* gp = src + (size_t)(rowbase + row) * DD + ko;
    short* dh = h + row * 136 + ko;
    short* dl = l + row * 136 + ko;
    #pragma unroll
    for (int j = 0; j < 4; j++) {
        float4 a = *reinterpret_cast<const float4*>(gp + j * 8);
        float4 b = *reinterpret_cast<const float4*>(gp + j * 8 + 4);
        float v[8] = {a.x, a.y, a.z, a.w, b.x, b.y, b.z, b.w};
        s16x8 hv, lv;
        #pragma unroll
        for (int e = 0; e < 8; e++) {
            short hh = f2bf(v[e]);
            hv[e] = hh;
            lv[e] = f2bf(v[e] - bf2f(hh));
        }
        *(s16x8*)(dh + j * 8) = hv;
        *(s16x8*)(dl + j * 8) = lv;
    }
}
// single-plane variant
__device__ __forceinline__ void stage64h(const float* __restrict__ src, int rowbase,
                                         short* __restrict__ h, int tid) {
    int row = tid >> 2, ko = (tid & 3) * 32;
    const float* gp = src + (size_t)(rowbase + row) * DD + ko;
    short* dh = h + row * 136 + ko;
    #pragma unroll
    for (int j = 0; j < 4; j++) {
        float4 a = *reinterpret_cast<const float4*>(gp + j * 8);
        float4 b = *reinterpret_cast<const float4*>(gp + j * 8 + 4);
        s16x8 hv;
        hv[0] = f2bf(a.x); hv[1] = f2bf(a.y); hv[2] = f2bf(a.z); hv[3] = f2bf(a.w);
        hv[4] = f2bf(b.x); hv[5] = f2bf(b.y); hv[6] = f2bf(b.z); hv[7] = f2bf(b.w);
        *(s16x8*)(dh + j * 8) = hv;
    }
}

// ---------- 64x128 GEMM pass, K=128, plain bf16 MFMA (1-term) ----------
// A in LDS [64][136] bf16; B = W^T hi-plane in global [128][wlen], k-offset koff.
// C/D layout [m89]: col = lane&15, row = (lane>>4)*4 + reg.
__device__ __forceinline__ void mfma_pass1(const short* __restrict__ a0,
                                           const short* __restrict__ Wh,
                                           int wlen, int koff, int w, int l16, int kg,
                                           fx4 acc[4][2]) {
    #pragma unroll
    for (int ks = 0; ks < 4; ks++) {
        s16x8 ah[4];
        #pragma unroll
        for (int mt = 0; mt < 4; mt++)
            ah[mt] = *(const s16x8*)(a0 + (mt * 16 + l16) * 136 + ks * 32 + kg * 8);
        #pragma unroll
        for (int nt = 0; nt < 2; nt++) {
            int col = w * 32 + nt * 16 + l16;
            s16x8 bh = *(const s16x8*)(Wh + col * wlen + koff + ks * 32 + kg * 8);
            #pragma unroll
            for (int mt = 0; mt < 4; mt++)
                acc[mt][nt] = __builtin_amdgcn_mfma_f32_16x16x32_bf16(ah[mt], bh, acc[mt][nt], 0, 0, 0);
        }
    }
}

// ---------- sage GEMMs + kq piggyback: io = LN(silu(agg@aggW + x@sageW + b)), wt = mean(k*q) ----------
// Diffuse paths (aggW/sageW) are plain bf16; kq path keeps hi/lo 3-term (sign-critical wt).
__global__ __launch_bounds__(256, 4) void k_sage2(
    const float* __restrict__ x,
    const short* __restrict__ aWh,
    const short* __restrict__ sWh,
    const short* __restrict__ kqh, const short* __restrict__ kql,
    const float* __restrict__ bias, const float* __restrict__ g, const float* __restrict__ bb,
    float* __restrict__ wt_total, float* __restrict__ iw0,
    float* __restrict__ io) {
    __shared__ __align__(16) short stg[2][64 * 136];   // 34816 B; f32 LN scratch aliases
    float* fscr = (float*)&stg[0][0];
    short* sh = &stg[0][0];
    short* sl = &stg[1][0];
    const int rowbase = blockIdx.x * 64;
    const int tid = threadIdx.x;
    const int w = tid >> 6, lane = tid & 63;
    const int l16 = lane & 15, kg = lane >> 4;

    fx4 acc[4][2];
    #pragma unroll
    for (int mt = 0; mt < 4; mt++)
        #pragma unroll
        for (int nt = 0; nt < 2; nt++) acc[mt][nt] = (fx4){0.f, 0.f, 0.f, 0.f};

    // ---- agg tile (from io, hi only) @ aggW ----
    stage64h(io, rowbase, sh, tid);
    __syncthreads();
    mfma_pass1(sh, aWh, 128, 0, w, l16, kg, acc);
    __syncthreads();

    // ---- x tile (hi/lo — kq needs lo) @ sageW + kq piggyback ----
    stage64(x, rowbase, sh, sl, tid);
    __syncthreads();
    mfma_pass1(sh, sWh, 128, 0, w, l16, kg, acc);

    fx4 acck[2];
    acck[0] = (fx4){0.f, 0.f, 0.f, 0.f};
    acck[1] = (fx4){0.f, 0.f, 0.f, 0.f};
    #pragma unroll
    for (int ks = 0; ks < 4; ks++) {
        int ao = (w * 16 + l16) * 136 + ks * 32 + kg * 8;
        s16x8 ah = *(const s16x8*)(sh + ao);
        s16x8 al = *(const s16x8*)(sl + ao);
        #pragma unroll
        for (int nt = 0; nt < 2; nt++) {
            int bo = (nt * 16 + l16) * 128 + ks * 32 + kg * 8;
            s16x8 bh = *(const s16x8*)(kqh + bo);
            s16x8 bl = *(const s16x8*)(kql + bo);
            acck[nt] = __builtin_amdgcn_mfma_f32_16x16x32_bf16(ah, bh, acck[nt], 0, 0, 0);
            acck[nt] = __builtin_amdgcn_mfma_f32_16x16x32_bf16(ah, bl, acck[nt], 0, 0, 0);
            acck[nt] = __builtin_amdgcn_mfma_f32_16x16x32_bf16(al, bh, acck[nt], 0, 0, 0);
        }
    }
    #pragma unroll
    for (int r = 0; r < 4; r++) {
        float pr = acck[0][r] * acck[1][r];
        pr += __shfl_xor(pr, 1, 64);
        pr += __shfl_xor(pr, 2, 64);
        pr += __shfl_xor(pr, 4, 64);
        pr += __shfl_xor(pr, 8, 64);
        if (l16 == 0) {
            int row = w * 16 + kg * 4 + r;
            int m = rowbase + row;
            int l = m / NN, n = m - l * NN;
            float sv = pr * (1.f / 16.f);
            wt_total[n * LL + l] = sv;
            iw0[n * LL + l] = sv;
        }
    }
    __syncthreads();   // all LDS reads done before fscr overwrite

    // ---- epilogue: +bias, silu -> fscr; LN -> io ----
    float bias_r[2];
    #pragma unroll
    for (int nt = 0; nt < 2; nt++) bias_r[nt] = bias[w * 32 + nt * 16 + l16];
    #pragma unroll
    for (int mt = 0; mt < 4; mt++) {
        #pragma unroll
        for (int r = 0; r < 4; r++) {
            int row = mt * 16 + kg * 4 + r;
            #pragma unroll
            for (int nt = 0; nt < 2; nt++) {
                int col = w * 32 + nt * 16 + l16;
                fscr[row * 129 + col] = silu(acc[mt][nt][r] + bias_r[nt]);
            }
        }
    }
    __syncthreads();
    {
        float g0 = g[lane], g1 = g[64 + lane];
        float b0 = bb[lane], b1 = bb[64 + lane];
        #pragma unroll 1
        for (int rr = 0; rr < 16; rr++) {
            int row = w * 16 + rr;
            size_t m = (size_t)rowbase + row;
            float y0 = fscr[row * 129 + lane], y1 = fscr[row * 129 + 64 + lane];
            float s = y0 + y1, q = y0 * y0 + y1 * y1;
            #pragma unroll
            for (int off = 32; off; off >>= 1) {
                s += __shfl_xor(s, off, 64);
                q += __shfl_xor(q, off, 64);
            }
            float mean = s * (1.f / 128.f);
            float var = fmaxf(q * (1.f / 128.f) - mean * mean, 0.f);
            float rstd = rsqrtf(var + EPSF);
            io[m * DD + lane]      = (y0 - mean) * rstd * g0 + b0;
            io[m * DD + 64 + lane] = (y1 - mean) * rstd * g1 + b1;
        }
    }
}

// ---------- fused lin1 + lin2, all-bf16 single-plane, in-place bf16 LN ----------
// Tiles: xt (x -> sage -> out-preLN), atl (v*ws -> attLN -> h1 -> ln1). 34816 B total.
__global__ __launch_bounds__(256, 4) void k_lin12(
    const float* __restrict__ x,
    const short* __restrict__ Wvh,
    const float* __restrict__ wtbuf,
    const float* __restrict__ att_g, const float* __restrict__ att_b,
    const short* __restrict__ W1h,                                   // [128][256] transposed
    const float* __restrict__ b1v,
    const float* __restrict__ ln1g, const float* __restrict__ ln1b,
    const short* __restrict__ W2h,                                   // [128][128] transposed
    const float* __restrict__ b2v,
    const float* __restrict__ ln2g, const float* __restrict__ ln2b,
    float* __restrict__ io) {                                        // sage in, out in-place
    __shared__ __align__(16) short xt[64 * 136];    // 17408 B
    __shared__ __align__(16) short atl[64 * 136];   // 17408 B
    const int rowbase = blockIdx.x * 64;
    const int tid = threadIdx.x;
    const int w = tid >> 6, lane = tid & 63;
    const int l16 = lane & 15, kg = lane >> 4;

    // T14: issue sage loads now; consumed at restage much later.
    float4 pf[8];
    {
        int row = tid >> 2, ko = (tid & 3) * 32;
        const float* gp = io + (size_t)(rowbase + row) * DD + ko;
        #pragma unroll
        for (int j = 0; j < 8; j++) pf[j] = *reinterpret_cast<const float4*>(gp + j * 4);
    }

    fx4 acc[4][2];
    #pragma unroll
    for (int mt = 0; mt < 4; mt++)
        #pragma unroll
        for (int nt = 0; nt < 2; nt++) acc[mt][nt] = (fx4){0.f, 0.f, 0.f, 0.f};

    // ---- att: v = x @ Wv;  v*ws -> atl (bf16) ----
    stage64h(x, rowbase, xt, tid);
    __syncthreads();
    mfma_pass1(xt, Wvh, 128, 0, w, l16, kg, acc);
    #pragma unroll
    for (int mt = 0; mt < 4; mt++) {
        #pragma unroll
        for (int r = 0; r < 4; r++) {
            int row = mt * 16 + kg * 4 + r;
            int m = rowbase + row;
            int l = m / NN, n = m - l * NN;
            float ws = wtbuf[n * LL + l];
            #pragma unroll
            for (int nt = 0; nt < 2; nt++) {
                int col = w * 32 + nt * 16 + l16;
                atl[row * 136 + col] = f2bf(acc[mt][nt][r] * ws);
            }
        }
    }
    __syncthreads();

    // ---- att LN in-place on atl  ∥  restage sage (pf regs) -> xt ----
    {
        float g0 = att_g[lane], g1 = att_g[64 + lane];
        float b0 = att_b[lane], b1 = att_b[64 + lane];
        #pragma unroll 1
        for (int rr = 0; rr < 16; rr++) {
            int row = w * 16 + rr;
            float y0 = bf2f(atl[row * 136 + lane]), y1 = bf2f(atl[row * 136 + 64 + lane]);
            float s = y0 + y1, q = y0 * y0 + y1 * y1;
            #pragma unroll
            for (int off = 32; off; off >>= 1) {
                s += __shfl_xor(s, off, 64);
                q += __shfl_xor(q, off, 64);
            }
            float mean = s * (1.f / 128.f);
            float var = fmaxf(q * (1.f / 128.f) - mean * mean, 0.f);
            float rstd = rsqrtf(var + EPSF);
            atl[row * 136 + lane]      = f2bf((y0 - mean) * rstd * g0 + b0);
            atl[row * 136 + 64 + lane] = f2bf((y1 - mean) * rstd * g1 + b1);
        }
    }
    {
        int row = tid >> 2, ko = (tid & 3) * 32;
        short* dh = xt + row * 136 + ko;
        #pragma unroll
        for (int j = 0; j < 4; j++) {
            float4 a = pf[2 * j], b = pf[2 * j + 1];
            s16x8 hv;
            hv[0] = f2bf(a.x); hv[1] = f2bf(a.y); hv[2] = f2bf(a.z); hv[3] = f2bf(a.w);
            hv[4] = f2bf(b.x); hv[5] = f2bf(b.y); hv[6] = f2bf(b.z); hv[7] = f2bf(b.w);
            *(s16x8*)(dh + j * 8) = hv;
        }
    }
    __syncthreads();

    // ---- h1 = sage(xt) @ W1[:,0:128] + att(atl) @ W1[:,128:256] ----
    #pragma unroll
    for (int mt = 0; mt < 4; mt++)
        #pragma unroll
        for (int nt = 0; nt < 2; nt++) acc[mt][nt] = (fx4){0.f, 0.f, 0.f, 0.f};
    mfma_pass1(xt, W1h, 256, 0, w, l16, kg, acc);
    mfma_pass1(atl, W1h, 256, 128, w, l16, kg, acc);
    __syncthreads();

    {   // silu(h1 + b1) -> atl (bf16)
        float bias_r[2];
        #pragma unroll
        for (int nt = 0; nt < 2; nt++) bias_r[nt] = b1v[w * 32 + nt * 16 + l16];
        #pragma unroll
        for (int mt = 0; mt < 4; mt++) {
            #pragma unroll
            for (int r = 0; r < 4; r++) {
                int row = mt * 16 + kg * 4 + r;
                #pragma unroll
                for (int nt = 0; nt < 2; nt++) {
                    int col = w * 32 + nt * 16 + l16;
                    atl[row * 136 + col] = f2bf(silu(acc[mt][nt][r] + bias_r[nt]));
                }
            }
        }
    }
    __syncthreads();
    {   // LN1 in-place on atl
        float g0 = ln1g[lane], g1 = ln1g[64 + lane];
        float b0 = ln1b[lane], b1 = ln1b[64 + lane];
        #pragma unroll 1
        for (int rr = 0; rr < 16; rr++) {
            int row = w * 16 + rr;
            float y0 = bf2f(atl[row * 136 + lane]), y1 = bf2f(atl[row * 136 + 64 + lane]);
            float s = y0 + y1, q = y0 * y0 + y1 * y1;
            #pragma unroll
            for (int off = 32; off; off >>= 1) {
                s += __shfl_xor(s, off, 64);
                q += __shfl_xor(q, off, 64);
            }
            float mean = s * (1.f / 128.f);
            float var = fmaxf(q * (1.f / 128.f) - mean * mean, 0.f);
            float rstd = rsqrtf(var + EPSF);
            atl[row * 136 + lane]      = f2bf((y0 - mean) * rstd * g0 + b0);
            atl[row * 136 + 64 + lane] = f2bf((y1 - mean) * rstd * g1 + b1);
        }
    }
    __syncthreads();

    // ---- out-preLN = silu(h1ln @ W2 + b2 + x) -> xt (bf16) ----
    #pragma unroll
    for (int mt = 0; mt < 4; mt++)
        #pragma unroll
        for (int nt = 0; nt < 2; nt++) acc[mt][nt] = (fx4){0.f, 0.f, 0.f, 0.f};
    mfma_pass1(atl, W2h, 128, 0, w, l16, kg, acc);
    {
        float bias_r[2];
        #pragma unroll
        for (int nt = 0; nt < 2; nt++) bias_r[nt] = b2v[w * 32 + nt * 16 + l16];
        #pragma unroll
        for (int mt = 0; mt < 4; mt++) {
            #pragma unroll
            for (int r = 0; r < 4; r++) {
                int row = mt * 16 + kg * 4 + r;
                size_t m = (size_t)rowbase + row;
                #pragma unroll
                for (int nt = 0; nt < 2; nt++) {
                    int col = w * 32 + nt * 16 + l16;
                    xt[row * 136 + col] = f2bf(silu(acc[mt][nt][r] + bias_r[nt] + x[m * DD + col]));
                }
            }
        }
    }
    __syncthreads();
    {   // final LN from xt -> io
        float g0 = ln2g[lane], g1 = ln2g[64 + lane];
        float b0 = ln2b[lane], b1 = ln2b[64 + lane];
        #pragma unroll 1
        for (int rr = 0; rr < 16; rr++) {
            int row = w * 16 + rr;
            size_t m = (size_t)rowbase + row;
            float y0 = bf2f(xt[row * 136 + lane]), y1 = bf2f(xt[row * 136 + 64 + lane]);
            float s = y0 + y1, q = y0 * y0 + y1 * y1;
            #pragma unroll
            for (int off = 32; off; off >>= 1) {
                s += __shfl_xor(s, off, 64);
                q += __shfl_xor(q, off, 64);
            }
            float mean = s * (1.f / 128.f);
            float var = fmaxf(q * (1.f / 128.f) - mean * mean, 0.f);
            float rstd = rsqrtf(var + EPSF);
            io[m * DD + lane]      = (y0 - mean) * rstd * g0 + b0;
            io[m * DD + 64 + lane] = (y1 - mean) * rstd * g1 + b1;
        }
    }
}

// ---------- retentive weight iteration (f32 vals — sign-critical) ----------
__global__ __launch_bounds__(256) void k_spmm_w(const int* __restrict__ offs,
                                                const int2* __restrict__ cpack,
                                                const float* __restrict__ win, float* __restrict__ wout,
                                                float* __restrict__ wtot) {
    int i = blockIdx.x * 256 + threadIdx.x;
    if (i >= NN * LL) return;
    int n = i >> 2, l = i & 3;
    int s = offs[n], e = offs[n + 1];
    float a = 0.f;
    for (int p = s; p < e; p++) {
        int2 cw = cpack[p];
        a += __int_as_float(cw.y) * win[(cw.x << 2) | l];
    }
    a *= DECAYF;
    wout[i] = a;
    wtot[i] += a;
}

extern "C" void kernel_launch(void* const* d_in, const int* in_sizes, int n_in,
                              void* d_out, int out_size, void* d_ws, size_t ws_size,
                              hipStream_t stream) {
    const float* x        = (const float*)d_in[0];
    const int*   ei       = (const int*)d_in[1];
    const float* evals    = (const float*)d_in[2];
    const float* sage_W   = (const float*)d_in[3];
    const float* sage_b   = (const float*)d_in[4];
    const float* sage_aggW= (const float*)d_in[5];
    const float* sage_ln_g= (const float*)d_in[6];
    const float* sage_ln_b= (const float*)d_in[7];
    const float* att_Wk   = (const float*)d_in[8];
    const float* att_Wq   = (const float*)d_in[9];
    const float* att_Wv   = (const float*)d_in[10];
    const float* att_ln_g = (const float*)d_in[11];
    const float* att_ln_b = (const float*)d_in[12];
    const float* lin1_W   = (const float*)d_in[13];
    const float* lin1_b   = (const float*)d_in[14];
    const float* lin2_W   = (const float*)d_in[15];
    const float* lin2_b   = (const float*)d_in[16];
    const float* ln1_g    = (const float*)d_in[17];
    const float* ln1_b    = (const float*)d_in[18];
    const float* ln2_g    = (const float*)d_in[19];
    const float* ln2_b    = (const float*)d_in[20];

    const int* rows = ei;
    const int* cols = ei + EE;

    // ---- workspace layout ----
    float* wt_total = (float*)d_ws;                       // [M]
    float* iw0      = wt_total + MM;
    float* iw1      = iw0 + MM;
    int*   counts   = (int*)(iw1 + MM);                   // N
    int*   offs     = counts + NN;                        // N+1
    int*   cursor   = offs + NN + 1;                      // N
    int*   csum     = cursor + NN;                        // 128
    uintptr_t pc    = (uintptr_t)(csum + 128);
    pc = (pc + 15) & ~(uintptr_t)15;
    int2*  cpack    = (int2*)pc;                          // E (col, f32 valbits)
    uintptr_t pw    = (uintptr_t)(cpack + EE);
    pw = (pw + 15) & ~(uintptr_t)15;
    short* wbf      = (short*)pw;                         // 204800 shorts
    uintptr_t ph    = (uintptr_t)(wbf + 204800);
    ph = (ph + 255) & ~(uintptr_t)255;
    __half* xh      = (__half*)ph;                        // M*D fp16 = 51.2 MB (optional)
    size_t need_h   = (ph - (uintptr_t)d_ws) + (size_t)MM * DD * sizeof(__half);
    bool use_half   = ws_size >= need_h;
    float* io       = (float*)d_out;                      // [M,D] f32: agg -> sage -> out

    // ---- weight transpose+split ----
    k_wprep<<<400, 256, 0, stream>>>(sage_W, sage_aggW, att_Wv, lin1_W, lin2_W,
                                     att_Wk, att_Wq, wbf);

    // ---- CSR build ----
    k_zero<<<(NN + 255) / 256, 256, 0, stream>>>(counts, NN);
    k_hist<<<(EE + 255) / 256, 256, 0, stream>>>(rows, counts);
    k_scan1<<<SCAN_NBLK, SCAN_CHUNK, 0, stream>>>(counts, offs, csum);
    k_scan2<<<1, 128, 0, stream>>>(csum);
    k_scan3<<<SCAN_NBLK, SCAN_CHUNK, 0, stream>>>(offs, csum, cursor);
    k_fill<<<(EE + 255) / 256, 256, 0, stream>>>(rows, cols, evals, cursor, cpack);

    // ---- SAGE aggregation -> io ----
    if (use_half) {
        k_xhalf<<<(MM * DD / 4 + 255) / 256, 256, 0, stream>>>(x, xh);
        k_agg_h<<<NN, 128, 0, stream>>>(offs, cpack, xh, io);
    } else {
        k_agg_f<<<NN, 128, 0, stream>>>(offs, cpack, x, io);
    }

    // ---- sage GEMMs + kq -> io in-place, wt_total/iw0 ----
    k_sage2<<<MM / 64, 256, 0, stream>>>(
        x,
        wbf + 32768,                   // aggW hi
        wbf,                           // sageW hi
        wbf + 196608, wbf + 200704,    // kq hi/lo
        sage_b, sage_ln_g, sage_ln_b,
        wt_total, iw0, io);

    // ---- retentive weight iterations ----
    k_spmm_w<<<(MM + 255) / 256, 256, 0, stream>>>(offs, cpack, iw0, iw1, wt_total);
    k_spmm_w<<<(MM + 255) / 256, 256, 0, stream>>>(offs, cpack, iw1, iw0, wt_total);

    // ---- fused lin1+lin2 -> io (= d_out) in-place ----
    k_lin12<<<MM / 64, 256, 0, stream>>>(
        x, wbf + 65536, wt_total, att_ln_g, att_ln_b,
        wbf + 98304, lin1_b, ln1_g, ln1_b,
        wbf + 163840, lin2_b, ln2_g, ln2_b,
        io);

    (void)in_sizes; (void)n_in; (void)out_size;
}